// Round 20
// baseline (1217.112 us; speedup 1.0000x reference)
//
#include <hip/hip_runtime.h>
#include <hip/hip_bf16.h>
#include <hip/hip_fp16.h>

// ---------------------------------------------------------------------------
// MGAN forward. fp16 MFMA; persistent LSTM scan, XCD-colocated sync groups.
//   B=256 S=128 A=8 L=32 D=H=300 NC=3 VOCAB=32000
// MFMA 16x16x32_f16 fragment scheme (validated rounds 2-19).
// P scan-order: Pscan[d][t'][b][1216]. Both weights fragment-major.
// Scan: ONE launch, 304 blocks, XCD swizzle lin = xcd + 8*(half*19 + js),
// group g = xcd + 8*half -> all 19 js-blocks of a sync group on ONE XCD.
// h: per-step unique single-writer lines hpad[t][d][20][256][16].
// Flags: per-group padded regions flags[g*128 + t] (r16).
// r20: PER-WAVE protocol — producer wave drains its own stores with
// s_waitcnt vmcnt(0) then lane0 adds +1 (relaxed/AGENT); consumer quorum 76
// (19 blocks x 4 waves). NO __syncthreads in the loop at all: kernel has no
// LDS / intra-block deps, so waves run fully decoupled. Same L2-local flag
// line, same step-unique h lines (r16/r17-proven); only drain granularity
// changes block->wave (vmcnt(0) = same "stores at L2" guarantee).
// Fast tanh via v_exp. emb16 pre-converted (overlay on hpadC).
// c_avg/a_avg folded into ctx_fused/combine_asp.
// ---------------------------------------------------------------------------

#define NB   256
#define NS   128
#define NA   8
#define NL   32
#define ND   300
#define NH   300
#define NPAD  2432      // 2*4*304 (bias/Wih padded n-space)
#define KP    320
#define TOK_CTX 32768
#define PD    1216      // per-dir gate row: 4*304
#define HCH   20        // h chunks per (t,d): 20*16 = 320 k-range
#define HSL   4096      // 256*16 halves per chunk

typedef _Float16 half8 __attribute__((ext_vector_type(8)));
typedef float    f32x4 __attribute__((ext_vector_type(4)));

__device__ __forceinline__ float fast_tanh(float x) {
  float e = __expf(-2.f * x);          // inf-safe: e=inf -> -1, e=0 -> +1
  return 2.f / (1.f + e) - 1.f;
}

// ---------------- K0: sequence lengths ----------------
__global__ void k_lengths(const int* __restrict__ text, const int* __restrict__ aspect,
                          const int* __restrict__ left, int* __restrict__ lens) {
  int b = threadIdx.x;
  if (b >= NB) return;
  int ll = 0; for (int i = 0; i < NL; i++) ll += (left[b*NL + i] != 0);
  int cl = 0; for (int i = 0; i < NS; i++) cl += (text[b*NS + i] != 0);
  int al = 0; for (int i = 0; i < NA; i++) al += (aspect[b*NA + i] != 0);
  lens[b] = ll; lens[NB + b] = cl; lens[2*NB + b] = al;
}

// ---------------- K0b: emb f32 -> fp16, K padded 300->320 ----------------
__global__ void k_cvt_emb(const float* __restrict__ emb, _Float16* __restrict__ emb16) {
  const long N = (long)32000 * KP;
  for (long i = (long)blockIdx.x*blockDim.x + threadIdx.x; i < N; i += (long)gridDim.x*blockDim.x) {
    long v = i / KP; int k = (int)(i - v*KP);
    emb16[i] = (k < ND) ? (_Float16)emb[v*ND + k] : (_Float16)0.f;
  }
}

// ---------------- converter: Wih_frag / Whh_frag / bias ----------------
__global__ void k_cvt_w(const float* __restrict__ Wih_f, const float* __restrict__ Wih_b,
                        const float* __restrict__ Whh_f, const float* __restrict__ Whh_b,
                        const float* __restrict__ bih_f, const float* __restrict__ bhh_f,
                        const float* __restrict__ bih_b, const float* __restrict__ bhh_b,
                        _Float16* __restrict__ Wih_frag, _Float16* __restrict__ Whh_frag,
                        float* __restrict__ bias_sum) {
  int y = blockIdx.y;
  if (y < 2) {
    const float* sf = y ? Whh_f : Wih_f;
    const float* sb = y ? Whh_b : Wih_b;
    _Float16* dst = y ? Whh_frag : Wih_frag;
    const long N = (long)152*10*512;   // 778240
    for (long i = (long)blockIdx.x*blockDim.x + threadIdx.x; i < N; i += (long)gridDim.x*blockDim.x) {
      long q = i >> 9; int r512 = (int)(i & 511);
      int l = r512 >> 3, e = r512 & 7;
      int k0 = (int)(q % 10);
      int ntile = (int)(q / 10);
      int n = ntile*16 + (l & 15);
      int k = k0*32 + (l >> 4)*8 + e;
      int d = n / PD; int rem = n - d*PD;
      int g = rem / 304; int jj = rem - g*304;
      float v = 0.f;
      if (jj < NH && k < NH) {
        const float* src = d ? sb : sf;
        v = src[(long)(g*NH + jj)*NH + k];
      }
      dst[i] = (_Float16)v;
    }
  } else {
    for (int i = blockIdx.x*blockDim.x + threadIdx.x; i < NPAD; i += gridDim.x*blockDim.x) {
      int d = i / PD; int rem = i - d*PD;
      int g = rem / 304; int jj = rem - g*304;
      float v = 0.f;
      if (jj < NH) {
        v = d ? (bih_b[g*NH + jj] + bhh_b[g*NH + jj]) : (bih_f[g*NH + jj] + bhh_f[g*NH + jj]);
      }
      bias_sum[i] = v;
    }
  }
}

// ---------------- K1: input projection GEMM (emb16 gather) ----------------
__global__ __launch_bounds__(256) void k_inproj(
    const _Float16* __restrict__ emb16, const int* __restrict__ text, const int* __restrict__ aspect,
    const _Float16* __restrict__ Wih_frag, const float* __restrict__ bias_sum,
    const int* __restrict__ lens,
    _Float16* __restrict__ Pc, _Float16* __restrict__ Pa)
{
  const int l = threadIdx.x & 63, w = threadIdx.x >> 6;
  const int m0 = blockIdx.x * 128, n0 = blockIdx.y * 128;
  const int lrow = l & 15, lk = (l >> 4) * 8;
  __shared__ __align__(16) _Float16 Cs[128*136];

  const _Float16* ap[2];
  #pragma unroll
  for (int q = 0; q < 2; q++) {
    int r = m0 + (2*w + q)*16 + lrow;
    int tok;
    if (r < TOK_CTX) { int t = r >> 8, b = r & 255; tok = text[b*NS + t]; }
    else { int rr = r - TOK_CTX; int t = rr >> 8, b = rr & 255; tok = aspect[b*NA + t]; }
    ap[q] = emb16 + (long)tok*KP + lk;
  }
  const _Float16* bp = Wih_frag + (size_t)(n0 >> 4)*10*512 + l*8;

  f32x4 acc[2][8];
  #pragma unroll
  for (int q = 0; q < 2; q++)
    #pragma unroll
    for (int nt = 0; nt < 8; nt++) acc[q][nt] = (f32x4){0.f,0.f,0.f,0.f};

  #pragma unroll
  for (int k0 = 0; k0 < 10; k0++) {
    half8 a0 = *(const half8*)(ap[0] + k0*32);
    half8 a1 = *(const half8*)(ap[1] + k0*32);
    #pragma unroll
    for (int nt = 0; nt < 8; nt++) {
      half8 bb = *(const half8*)(bp + (size_t)(nt*10 + k0)*512);
      acc[0][nt] = __builtin_amdgcn_mfma_f32_16x16x32_f16(a0, bb, acc[0][nt], 0, 0, 0);
      acc[1][nt] = __builtin_amdgcn_mfma_f32_16x16x32_f16(a1, bb, acc[1][nt], 0, 0, 0);
    }
  }

  #pragma unroll
  for (int nt = 0; nt < 8; nt++) {
    float bias = bias_sum[n0 + nt*16 + lrow];
    #pragma unroll
    for (int q = 0; q < 2; q++) {
      int lr = (2*w + q)*16 + (l>>4)*4;
      #pragma unroll
      for (int r = 0; r < 4; r++)
        Cs[(lr + r)*136 + nt*16 + lrow] = (_Float16)(acc[q][nt][r] + bias);
    }
  }
  __syncthreads();

  const bool isCtx = (m0 < TOK_CTX);
  _Float16* __restrict__ Pdst = isCtx ? Pc : Pa;
  const int T2 = isCtx ? NS : NA;
  const int mrel = isCtx ? m0 : (m0 - TOK_CTX);
  const int tq = mrel >> 8;
  const int b_base = mrel & 255;
  const int lenoff = isCtx ? NB : 2*NB;
  const int chunk = l & 15;
  const int col = n0 + chunk*8;
  const int d = (col >= PD) ? 1 : 0;
  const int rem = col - d*PD;
  #pragma unroll
  for (int it = 0; it < 8; it++) {
    const int row = w*32 + it*4 + (l >> 4);
    const int b = b_base + row;
    int tp = tq; bool doit = true;
    if (d == 1) {
      int len = lens[lenoff + b];
      if (tq < len) tp = len - 1 - tq; else doit = false;
    }
    if (doit) {
      half8 v = *(const half8*)&Cs[row*136 + chunk*8];
      *(half8*)&Pdst[((size_t)(d*T2 + tp)*256 + b)*PD + rem] = v;
    }
  }
}

// ---------------- K2: persistent LSTM scan, per-wave flags (no barriers) ----
__global__ __launch_bounds__(256) void k_lstm_scan(
    const _Float16* __restrict__ Pc, const _Float16* __restrict__ Pa,
    const _Float16* __restrict__ Whh_frag, const int* __restrict__ lens,
    _Float16* __restrict__ hpadC, _Float16* __restrict__ hpadA,
    int* __restrict__ flags)   // [16*128] ints, zeroed before launch
{
  const int lin = blockIdx.x;
  const int xcd = lin & 7;
  const int kk2 = lin >> 3;        // 0..37
  const int half = kk2 / 19;
  const int js = kk2 - half*19;
  const int g  = xcd + 8*half;     // 0..15
  const int which = g >> 3;
  const int d  = (g >> 2) & 1;
  const int mg = g & 3;

  const int l = threadIdx.x & 63, w = threadIdx.x >> 6;
  const int T = which ? NA : NS;
  const _Float16* __restrict__ Pbase = which ? Pa : Pc;
  const int* __restrict__ lenp = lens + (which ? 2*NB : NB);
  _Float16* __restrict__ hpad = which ? hpadA : hpadC;
  int* __restrict__ flg = flags + g*128;   // this group's private flag region

  const int lrow = l & 15, lk = (l >> 4)*8, mrow = l >> 4;
  const int b0 = mg*64 + w*16;
  const int cbase = lk >> 4;   // 0/1
  const int koff  = lk & 8;

  // preload this block's Whh fragments into registers (40 x half8)
  half8 wf[10][4];
  #pragma unroll
  for (int k0 = 0; k0 < 10; k0++)
    #pragma unroll
    for (int gg = 0; gg < 4; gg++)
      wf[k0][gg] = *(const half8*)(Whh_frag +
          ((((size_t)(d*4 + gg)*19 + js)*10 + k0) << 9) + l*8);

  float cst[4];
  int   lenv[4];
  #pragma unroll
  for (int r = 0; r < 4; r++) { cst[r] = 0.f; lenv[r] = lenp[b0 + mrow*4 + r]; }

  for (int t = 0; t < T; t++) {
    // prefetch this step's P gates (independent of h; hides the spin)
    const size_t slab = (size_t)(d*T + t)*256;
    float pre[4][4];
    #pragma unroll
    for (int r = 0; r < 4; r++) {
      const int b = b0 + mrow*4 + r;
      const _Float16* Pr = Pbase + (slab + b)*PD + js*16 + lrow;
      pre[r][0] = (float)Pr[0];
      pre[r][1] = (float)Pr[304];
      pre[r][2] = (float)Pr[608];
      pre[r][3] = (float)Pr[912];
    }

    f32x4 accA[4], accB[4];
    #pragma unroll
    for (int gg = 0; gg < 4; gg++) {
      accA[gg] = (f32x4){0.f,0.f,0.f,0.f};
      accB[gg] = (f32x4){0.f,0.f,0.f,0.f};
    }
    float hp[4] = {0.f, 0.f, 0.f, 0.f};

    if (t > 0) {
      // wave-decoupled poll (AGENT scope -> L2); quorum = 76 producer waves.
      if (l == 0) {
        int* fp = &flg[t-1];
        while (__hip_atomic_load(fp, __ATOMIC_RELAXED, __HIP_MEMORY_SCOPE_AGENT) < 76)
          __builtin_amdgcn_s_sleep(1);
      }
      const _Float16* __restrict__ hprev = hpad + (size_t)((t-1)*2 + d)*HCH*HSL;
      #pragma unroll
      for (int r = 0; r < 4; r++)
        hp[r] = (float)hprev[(size_t)js*HSL + (b0 + mrow*4 + r)*16 + lrow];
      const _Float16* hb = hprev + (size_t)(b0 + lrow)*16 + koff;
      #pragma unroll
      for (int k0 = 0; k0 < 10; k0 += 2) {
        half8 aE = *(const half8*)(hb + (size_t)(2*k0 + cbase)*HSL);
        half8 aO = *(const half8*)(hb + (size_t)(2*(k0+1) + cbase)*HSL);
        #pragma unroll
        for (int gg = 0; gg < 4; gg++) {
          accA[gg] = __builtin_amdgcn_mfma_f32_16x16x32_f16(aE, wf[k0][gg],   accA[gg], 0, 0, 0);
          accB[gg] = __builtin_amdgcn_mfma_f32_16x16x32_f16(aO, wf[k0+1][gg], accB[gg], 0, 0, 0);
        }
      }
    }

    // pointwise: 4 cells per thread; write h2 to this step's unique slab
    _Float16* __restrict__ hw = hpad + (size_t)(t*2 + d)*HCH*HSL + (size_t)js*HSL;
    #pragma unroll
    for (int r = 0; r < 4; r++) {
      const int b = b0 + mrow*4 + r;
      float gi = (accA[0][r] + accB[0][r]) + pre[r][0];
      float gf = (accA[1][r] + accB[1][r]) + pre[r][1];
      float gg2 = (accA[2][r] + accB[2][r]) + pre[r][2];
      float go = (accA[3][r] + accB[3][r]) + pre[r][3];
      float si = 1.f/(1.f + __expf(-gi));
      float sf = 1.f/(1.f + __expf(-gf));
      float so = 1.f/(1.f + __expf(-go));
      float cn = sf*cst[r] + si*fast_tanh(gg2);
      float hn = so*fast_tanh(cn);
      bool mt = t < lenv[r];
      float h2 = mt ? hn : hp[r];
      cst[r] = mt ? cn : cst[r];
      hw[(size_t)b*16 + lrow] = (_Float16)h2;
    }

    // per-wave drain: this wave's h stores reach L2, then lane0 adds.
    asm volatile("s_waitcnt vmcnt(0)" ::: "memory");
    if (l == 0)
      __hip_atomic_fetch_add(&flg[t], 1,
                             __ATOMIC_RELAXED, __HIP_MEMORY_SCOPE_AGENT);
  }
}

// ---------------- K3: fused combine + position weight + transpose + c_avg ----
__global__ __launch_bounds__(256) void k_ctx_fused(
    const _Float16* __restrict__ hpadC, const int* __restrict__ lens,
    _Float16* __restrict__ ctx, _Float16* __restrict__ ctxT, float* __restrict__ c_avg)
{
  const int b = blockIdx.x, tid = threadIdx.x;
  __shared__ float wgt_s[128];
  __shared__ int   tbv[128];
  __shared__ _Float16 tl[128][62];
  const int cl = lens[NB + b];
  if (tid < 128) {
    const int ll = lens[b], al = lens[2*NB + b];
    float clf = (float)cl, llf = (float)ll, alf = (float)al, tf = (float)tid;
    float denom = clf - alf + 1.f;
    float wgt = (tf < llf) ? (1.f - (llf - tf)/denom)
              : (tf < llf + alf) ? 0.f
              : (tf < clf) ? (1.f - (tf - llf - alf + 1.f)/denom) : 0.f;
    wgt_s[tid] = wgt;
    int tb0 = cl - 1 - tid; tbv[tid] = tb0 < 0 ? 0 : (tb0 > NS-1 ? NS-1 : tb0);
  }
  __syncthreads();
  const float clinv = 1.f / (float)cl;
  for (int c10 = 0; c10 < 10; c10++) {
    const int j0 = c10*60;
    for (int idx = tid; idx < 128*60; idx += 256) {
      int s = idx / 60, jc = idx - s*60;
      int j = j0 + jc;
      float v;
      if (j < NH) {
        int c = j >> 4, ww = j & 15;
        v = (float)hpadC[(((size_t)(s*2 + 0)*HCH + c)*256 + b)*16 + ww];
      } else {
        int j2 = j - NH; int c = j2 >> 4, ww = j2 & 15;
        v = (float)hpadC[(((size_t)(tbv[s]*2 + 1)*HCH + c)*256 + b)*16 + ww];
      }
      v *= wgt_s[s];
      tl[s][jc] = (_Float16)v;
      ctx[((size_t)b*NS + s)*600 + j] = (_Float16)v;
    }
    __syncthreads();
    for (int idx = tid; idx < 60*128; idx += 256) {
      int jc = idx >> 7, s = idx & 127;
      ctxT[((size_t)b*600 + j0 + jc)*NS + s] = tl[s][jc];
    }
    if (tid < 60) {
      float sum = 0.f;
      for (int s = 0; s < 128; s++) sum += (float)tl[s][tid];
      c_avg[(size_t)b*600 + j0 + tid] = sum * clinv;
    }
    __syncthreads();
  }
}

// ---------------- K4: aspect combine + a_avg -> aspc[b][a][600] ----------------
__global__ __launch_bounds__(320) void k_combine_asp(
    const _Float16* __restrict__ hpadA, const int* __restrict__ lens,
    _Float16* __restrict__ aspc, float* __restrict__ a_avg)
{
  int b = blockIdx.x, tid = threadIdx.x;
  if (tid >= NH) return;
  int al = lens[2*NB + b];
  const float alinv = 1.f / (float)al;
  const int c = tid >> 4, ww = tid & 15;
  float sumF = 0.f, sumB = 0.f;
  for (int a = 0; a < NA; a++) {
    float vf = (a < al) ? (float)hpadA[(((size_t)(a*2 + 0)*HCH + c)*256 + b)*16 + ww] : 0.f;
    int tb0 = al - 1 - a; int tb = tb0 < 0 ? 0 : (tb0 > NA-1 ? NA-1 : tb0);
    float vb = (a < al) ? (float)hpadA[(((size_t)(tb*2 + 1)*HCH + c)*256 + b)*16 + ww] : 0.f;
    aspc[((size_t)b*NA + a)*600 + tid]      = (_Float16)vf;
    aspc[((size_t)b*NA + a)*600 + NH + tid] = (_Float16)vb;
    sumF += vf; sumB += vb;
  }
  a_avg[(size_t)b*600 + tid]      = sumF * alinv;
  a_avg[(size_t)b*600 + NH + tid] = sumB * alinv;
}

// ---------------- K6: s1 = a_avg@w1 ; s2 = c_avg@w2 ----------------
__global__ void k_sw(const float* __restrict__ a_avg, const float* __restrict__ c_avg,
                     const float* __restrict__ w1, const float* __restrict__ w2,
                     float* __restrict__ s1, float* __restrict__ s2) {
  __shared__ float src[8][600];
  int bg = blockIdx.x * 8, which = blockIdx.y, tid = threadIdx.x;
  const float* sp = which ? c_avg : a_avg;
  const float* w  = which ? w2 : w1;
  float* outp     = which ? s2 : s1;
  for (int u = tid; u < 8*600; u += 640) {
    int q = u / 600, dd = u - q*600;
    src[q][dd] = sp[(long)(bg + q)*600 + dd];
  }
  __syncthreads();
  int j = tid;
  if (j >= 600) return;
  float acc[8] = {0,0,0,0,0,0,0,0};
  for (int dd = 0; dd < 600; dd++) {
    float wvv = w[dd*600 + j];
    #pragma unroll
    for (int q = 0; q < 8; q++) acc[q] += src[q][dd] * wvv;
  }
  #pragma unroll
  for (int q = 0; q < 8; q++) outp[(long)(bg + q)*600 + j] = acc[q];
}

// ---------------- K7: alpha1 + mca ----------------
__global__ __launch_bounds__(128) void k_att_ctx(const _Float16* __restrict__ ctxT,
    const _Float16* __restrict__ ctx, const float* __restrict__ s1, float* __restrict__ mca) {
  int b = blockIdx.x, tid = threadIdx.x;
  __shared__ float sv[600];
  __shared__ float red[128];
  __shared__ float mx, sm;
  for (int u = tid; u < 600; u += 128) sv[u] = s1[(long)b*600 + u];
  __syncthreads();
  float sc = 0.f;
  for (int dd = 0; dd < 600; dd++) sc += sv[dd] * (float)ctxT[((long)b*600 + dd)*NS + tid];
  red[tid] = sc; __syncthreads();
  if (tid == 0) { float m = -1e30f; for (int i = 0; i < 128; i++) m = fmaxf(m, red[i]); mx = m; }
  __syncthreads();
  float e = __expf(sc - mx);
  red[tid] = e; __syncthreads();
  if (tid == 0) { float s = 0.f; for (int i = 0; i < 128; i++) s += red[i]; sm = s; }
  __syncthreads();
  float alpha = e / sm;
  red[tid] = alpha; __syncthreads();
  for (int i = 0; i < 5; i++) {
    int j = tid + i*128;
    if (j < 600) {
      float acc = 0.f;
      for (int s2 = 0; s2 < NS; s2++) acc += red[s2] * (float)ctx[((long)b*NS + s2)*600 + j];
      mca[(long)b*600 + j] = acc;
    }
  }
}

// ---------------- K8: alpha2 + mcc ----------------
__global__ void k_att_asp(const _Float16* __restrict__ aspc, const float* __restrict__ s2,
                          float* __restrict__ mcc) {
  int b = blockIdx.x, tid = threadIdx.x, wvv = tid >> 6, lane = tid & 63;
  __shared__ float sv[600];
  __shared__ float sc8[8];
  for (int u = tid; u < 600; u += 512) sv[u] = s2[(long)b*600 + u];
  __syncthreads();
  float p = 0.f;
  for (int dd = lane; dd < 600; dd += 64) p += sv[dd] * (float)aspc[((long)b*NA + wvv)*600 + dd];
  #pragma unroll
  for (int off = 32; off; off >>= 1) p += __shfl_down(p, off);
  if (lane == 0) sc8[wvv] = p;
  __syncthreads();
  float m = -1e30f;
  #pragma unroll
  for (int a = 0; a < 8; a++) m = fmaxf(m, sc8[a]);
  float es[8]; float ssum = 0.f;
  #pragma unroll
  for (int a = 0; a < 8; a++) { es[a] = __expf(sc8[a] - m); ssum += es[a]; }
  float inv = 1.f / ssum;
  for (int i = 0; i < 2; i++) {
    int j = tid + i*512;
    if (j < 600) {
      float acc = 0.f;
      #pragma unroll
      for (int a = 0; a < 8; a++) acc += es[a]*inv * (float)aspc[((long)b*NA + a)*600 + j];
      mcc[(long)b*600 + j] = acc;
    }
  }
}

// ---------------- K9: u tensor -> mfa, mfc ----------------
__global__ __launch_bounds__(128) void k_u(const _Float16* __restrict__ ctxT, const _Float16* __restrict__ ctx,
    const _Float16* __restrict__ aspc, const float* __restrict__ fc1_w, const float* __restrict__ fc1_b,
    float* __restrict__ mfa, float* __restrict__ mfc) {
  int b = blockIdx.x, tid = threadIdx.x;   // tid == s
  __shared__ __align__(16) float aspl[4800];
  __shared__ float ua8[8];
  __shared__ float red[128];
  __shared__ float qa8[8];
  __shared__ float mx1, sm1;
  __shared__ float pal[128][8];
  for (int u = tid; u < 4800; u += 128) {
    int a = u / 600, dd = u - a*600;
    aspl[dd*8 + a] = (float)aspc[((long)b*NA + a)*600 + dd];
  }
  __syncthreads();
  const float* wc = fc1_w;
  const float* wa = fc1_w + 600;
  const float* wm = fc1_w + 1200;
  {
    int wvv = tid >> 6, lane = tid & 63;
    for (int q = 0; q < 4; q++) {
      int a = wvv*4 + q;
      float p = 0.f;
      for (int dd = lane; dd < 600; dd += 64) p += wa[dd] * aspl[dd*8 + a];
      #pragma unroll
      for (int off = 32; off; off >>= 1) p += __shfl_down(p, off);
      if (lane == 0) ua8[a] = p;
    }
  }
  __syncthreads();
  float x8[8] = {0,0,0,0,0,0,0,0};
  float uc = 0.f;
  for (int dd = 0; dd < 600; dd++) {
    float cv = (float)ctxT[((long)b*600 + dd)*NS + tid];
    uc += cv * wc[dd];
    float cm = cv * wm[dd];
    float4 a03 = *(const float4*)&aspl[dd*8];
    float4 a47 = *(const float4*)&aspl[dd*8 + 4];
    x8[0] += cm*a03.x; x8[1] += cm*a03.y; x8[2] += cm*a03.z; x8[3] += cm*a03.w;
    x8[4] += cm*a47.x; x8[5] += cm*a47.y; x8[6] += cm*a47.z; x8[7] += cm*a47.w;
  }
  float fb = fc1_b[0];
  float u8v[8]; float umax = -1e30f;
  #pragma unroll
  for (int a = 0; a < 8; a++) { u8v[a] = uc + ua8[a] + x8[a] + fb; umax = fmaxf(umax, u8v[a]); }
  float pa[8]; float psum = 0.f;
  #pragma unroll
  for (int a = 0; a < 8; a++) { pa[a] = __expf(u8v[a] - umax); psum += pa[a]; }
  float pin = 1.f / psum;
  #pragma unroll
  for (int a = 0; a < 8; a++) pal[tid][a] = pa[a] * pin;
  red[tid] = umax;
  __syncthreads();
  if (tid == 0) { float m = -1e30f; for (int i = 0; i < 128; i++) m = fmaxf(m, red[i]); mx1 = m; }
  if (tid < 8) { float s = 0.f; for (int i = 0; i < 128; i++) s += pal[i][tid]; qa8[tid] = s * (1.f/128.f); }
  __syncthreads();
  float e = __expf(umax - mx1);
  red[tid] = e;
  __syncthreads();
  if (tid == 0) { float s = 0.f; for (int i = 0; i < 128; i++) s += red[i]; sm1 = s; }
  __syncthreads();
  float alpha = e / sm1;
  red[tid] = alpha;
  __syncthreads();
  for (int i = 0; i < 5; i++) {
    int j = tid + i*128;
    if (j < 600) {
      float am = 0.f;
      for (int s2 = 0; s2 < NS; s2++) am += red[s2] * (float)ctx[((long)b*NS + s2)*600 + j];
      float4 a03 = *(const float4*)&aspl[j*8];
      float4 a47 = *(const float4*)&aspl[j*8 + 4];
      mfa[(long)b*600 + j] = am;
      mfc[(long)b*600 + j] = qa8[0]*a03.x + qa8[1]*a03.y + qa8[2]*a03.z + qa8[3]*a03.w
                           + qa8[4]*a47.x + qa8[5]*a47.y + qa8[6]*a47.z + qa8[7]*a47.w;
    }
  }
}

// ---------------- K10: final FC + softmax ----------------
__global__ void k_final(const float* __restrict__ mca, const float* __restrict__ mcc,
                        const float* __restrict__ mfa, const float* __restrict__ mfc,
                        const float* __restrict__ fc2_w, const float* __restrict__ fc2_b,
                        float* __restrict__ out) {
  int b = blockIdx.x, tid = threadIdx.x, c = tid >> 6, lane = tid & 63;
  __shared__ float lg[3];
  float p = 0.f;
  for (int u = lane; u < 2400; u += 64) {
    int piece = u / 600;
    int jj = u - piece*600;
    const float* src = (piece == 0) ? mca : (piece == 1) ? mcc : (piece == 2) ? mfa : mfc;
    p += src[(long)b*600 + jj] * fc2_w[c*2400 + u];
  }
  #pragma unroll
  for (int off = 32; off; off >>= 1) p += __shfl_down(p, off);
  if (lane == 0) lg[c] = p + fc2_b[c];
  __syncthreads();
  if (tid == 0) {
    float m = fmaxf(lg[0], fmaxf(lg[1], lg[2]));
    float e0 = __expf(lg[0]-m), e1 = __expf(lg[1]-m), e2 = __expf(lg[2]-m);
    float s = e0 + e1 + e2;
    out[b*3 + 0] = e0/s; out[b*3 + 1] = e1/s; out[b*3 + 2] = e2/s;
  }
}

// ---------------- host ----------------
extern "C" void kernel_launch(void* const* d_in, const int* in_sizes, int n_in,
                              void* d_out, int out_size, void* d_ws, size_t ws_size,
                              hipStream_t stream)
{
  const int*   text    = (const int*)d_in[0];
  const int*   aspect  = (const int*)d_in[1];
  const int*   left    = (const int*)d_in[2];
  const float* emb     = (const float*)d_in[3];
  const float* Wih_f   = (const float*)d_in[4];
  const float* Whh_f   = (const float*)d_in[5];
  const float* bih_f   = (const float*)d_in[6];
  const float* bhh_f   = (const float*)d_in[7];
  const float* Wih_b   = (const float*)d_in[8];
  const float* Whh_b   = (const float*)d_in[9];
  const float* bih_b   = (const float*)d_in[10];
  const float* bhh_b   = (const float*)d_in[11];
  const float* w1      = (const float*)d_in[12];
  const float* w2      = (const float*)d_in[13];
  const float* fc1_w   = (const float*)d_in[14];
  const float* fc1_b   = (const float*)d_in[15];
  const float* fc2_w   = (const float*)d_in[16];
  const float* fc2_b   = (const float*)d_in[17];
  float* out = (float*)d_out;

  char* base = (char*)d_ws;
  size_t off = 0;
  auto alloc = [&](size_t bytes) -> void* {
    void* p = base + off;
    off = (off + bytes + 255) & ~(size_t)255;
    return p;
  };
  int*      lens     = (int*)     alloc(3 * NB * sizeof(int));
  int*      flags    = (int*)     alloc((size_t)16*128 * sizeof(int));            // 8 KB padded
  float*    bias_sum = (float*)   alloc(NPAD * sizeof(float));
  _Float16* Wih_frag = (_Float16*)alloc((size_t)152*10*512 * sizeof(_Float16));   // 1.56 MB
  _Float16* Whh_frag = (_Float16*)alloc((size_t)152*10*512 * sizeof(_Float16));   // 1.56 MB
  float*    c_avg    = (float*)   alloc((size_t)NB*600 * sizeof(float));
  float*    a_avg    = (float*)   alloc((size_t)NB*600 * sizeof(float));
  float*    s1       = (float*)   alloc((size_t)NB*600 * sizeof(float));
  float*    s2       = (float*)   alloc((size_t)NB*600 * sizeof(float));
  float*    mca      = (float*)   alloc((size_t)NB*600 * sizeof(float));
  float*    mcc      = (float*)   alloc((size_t)NB*600 * sizeof(float));
  float*    mfa      = (float*)   alloc((size_t)NB*600 * sizeof(float));
  float*    mfc      = (float*)   alloc((size_t)NB*600 * sizeof(float));
  _Float16* hpadC    = (_Float16*)alloc((size_t)NS*2*HCH*HSL * sizeof(_Float16)); // 41.9 MB
  _Float16* hpadA    = (_Float16*)alloc((size_t)NA*2*HCH*HSL * sizeof(_Float16)); // 2.62 MB
  // emb16 (20.5 MB) overlays hpadC: used only by cvt_emb+inproj (before scan)
  _Float16* emb16    = hpadC;
  // BIG region: Pc (159.4 MB) + Pa (10 MB); ctx/ctxT/aspc (81 MB) overlay Pc later
  _Float16* Pc = (_Float16*)alloc((size_t)2*NS*NB*PD * sizeof(_Float16));
  _Float16* Pa = (_Float16*)alloc((size_t)2*NA*NB*PD * sizeof(_Float16));
  _Float16* ctx  = Pc;
  _Float16* ctxT = ctx  + (size_t)NB*NS*600;
  _Float16* aspc = ctxT + (size_t)NB*NS*600;
  if (ws_size < off) return;  // clean zero-output signal instead of OOB

  k_lengths<<<1, 256, 0, stream>>>(text, aspect, left, lens);
  k_cvt_emb<<<2048, 256, 0, stream>>>(emb, emb16);
  k_cvt_w<<<dim3(512, 3), 256, 0, stream>>>(Wih_f, Wih_b, Whh_f, Whh_b,
                                            bih_f, bhh_f, bih_b, bhh_b,
                                            Wih_frag, Whh_frag, bias_sum);
  k_inproj<<<dim3(272, 19), 256, 0, stream>>>(emb16, text, aspect, Wih_frag, bias_sum,
                                              lens, Pc, Pa);

  hipMemsetAsync(flags, 0, (size_t)16*128 * sizeof(int), stream);
  k_lstm_scan<<<304, 256, 0, stream>>>(Pc, Pa, Whh_frag, lens, hpadC, hpadA, flags);

  k_ctx_fused<<<256, 256, 0, stream>>>(hpadC, lens, ctx, ctxT, c_avg);
  k_combine_asp<<<256, 320, 0, stream>>>(hpadA, lens, aspc, a_avg);
  k_sw<<<dim3(32, 2), 640, 0, stream>>>(a_avg, c_avg, w1, w2, s1, s2);
  k_att_ctx<<<256, 128, 0, stream>>>(ctxT, ctx, s1, mca);
  k_att_asp<<<256, 512, 0, stream>>>(aspc, s2, mcc);
  k_u<<<256, 128, 0, stream>>>(ctxT, ctx, aspc, fc1_w, fc1_b, mfa, mfc);
  k_final<<<256, 192, 0, stream>>>(mca, mcc, mfa, mfc, fc2_w, fc2_b, out);
}

// Round 21
// 1091.282 us; speedup vs baseline: 1.1153x; 1.1153x over previous
//
#include <hip/hip_runtime.h>
#include <hip/hip_bf16.h>
#include <hip/hip_fp16.h>

// ---------------------------------------------------------------------------
// MGAN forward. fp16 MFMA; persistent LSTM scan, XCD-colocated sync groups.
//   B=256 S=128 A=8 L=32 D=H=300 NC=3 VOCAB=32000
// MFMA 16x16x32_f16 fragment scheme (validated rounds 2-19).
// P scan-order: Pscan[d][t'][b][1216]. Both weights fragment-major.
// Scan: ONE launch, 304 blocks, XCD swizzle lin = xcd + 8*(half*19 + js),
// group g = xcd + 8*half -> all 19 js-blocks of a sync group on ONE XCD.
// h: per-step unique single-writer lines hpad[t][d][20][256][16].
// Flags: per-group padded regions flags[g*128 + t] (r16).
// r21 = r19 protocol (BEST measured: scan 519us / total 1062us):
//   consumers: lane0-per-wave poll, RELAXED/AGENT, quorum 19 (waves decouple)
//   producers: __syncthreads (block store drain) + single thread0 add
// r20's per-wave flags (quorum 76) REGRESSED: 4x flag-line atomic ops/step
// dominate -> flag op COUNT, not drain granularity, sets the sync cost.
// Fast tanh via v_exp. emb16 pre-converted (overlay on hpadC).
// c_avg/a_avg folded into ctx_fused/combine_asp.
// ---------------------------------------------------------------------------

#define NB   256
#define NS   128
#define NA   8
#define NL   32
#define ND   300
#define NH   300
#define NPAD  2432      // 2*4*304 (bias/Wih padded n-space)
#define KP    320
#define TOK_CTX 32768
#define PD    1216      // per-dir gate row: 4*304
#define HCH   20        // h chunks per (t,d): 20*16 = 320 k-range
#define HSL   4096      // 256*16 halves per chunk

typedef _Float16 half8 __attribute__((ext_vector_type(8)));
typedef float    f32x4 __attribute__((ext_vector_type(4)));

__device__ __forceinline__ float fast_tanh(float x) {
  float e = __expf(-2.f * x);          // inf-safe: e=inf -> -1, e=0 -> +1
  return 2.f / (1.f + e) - 1.f;
}

// ---------------- K0: sequence lengths ----------------
__global__ void k_lengths(const int* __restrict__ text, const int* __restrict__ aspect,
                          const int* __restrict__ left, int* __restrict__ lens) {
  int b = threadIdx.x;
  if (b >= NB) return;
  int ll = 0; for (int i = 0; i < NL; i++) ll += (left[b*NL + i] != 0);
  int cl = 0; for (int i = 0; i < NS; i++) cl += (text[b*NS + i] != 0);
  int al = 0; for (int i = 0; i < NA; i++) al += (aspect[b*NA + i] != 0);
  lens[b] = ll; lens[NB + b] = cl; lens[2*NB + b] = al;
}

// ---------------- K0b: emb f32 -> fp16, K padded 300->320 ----------------
__global__ void k_cvt_emb(const float* __restrict__ emb, _Float16* __restrict__ emb16) {
  const long N = (long)32000 * KP;
  for (long i = (long)blockIdx.x*blockDim.x + threadIdx.x; i < N; i += (long)gridDim.x*blockDim.x) {
    long v = i / KP; int k = (int)(i - v*KP);
    emb16[i] = (k < ND) ? (_Float16)emb[v*ND + k] : (_Float16)0.f;
  }
}

// ---------------- converter: Wih_frag / Whh_frag / bias ----------------
__global__ void k_cvt_w(const float* __restrict__ Wih_f, const float* __restrict__ Wih_b,
                        const float* __restrict__ Whh_f, const float* __restrict__ Whh_b,
                        const float* __restrict__ bih_f, const float* __restrict__ bhh_f,
                        const float* __restrict__ bih_b, const float* __restrict__ bhh_b,
                        _Float16* __restrict__ Wih_frag, _Float16* __restrict__ Whh_frag,
                        float* __restrict__ bias_sum) {
  int y = blockIdx.y;
  if (y < 2) {
    const float* sf = y ? Whh_f : Wih_f;
    const float* sb = y ? Whh_b : Wih_b;
    _Float16* dst = y ? Whh_frag : Wih_frag;
    const long N = (long)152*10*512;   // 778240
    for (long i = (long)blockIdx.x*blockDim.x + threadIdx.x; i < N; i += (long)gridDim.x*blockDim.x) {
      long q = i >> 9; int r512 = (int)(i & 511);
      int l = r512 >> 3, e = r512 & 7;
      int k0 = (int)(q % 10);
      int ntile = (int)(q / 10);
      int n = ntile*16 + (l & 15);
      int k = k0*32 + (l >> 4)*8 + e;
      int d = n / PD; int rem = n - d*PD;
      int g = rem / 304; int jj = rem - g*304;
      float v = 0.f;
      if (jj < NH && k < NH) {
        const float* src = d ? sb : sf;
        v = src[(long)(g*NH + jj)*NH + k];
      }
      dst[i] = (_Float16)v;
    }
  } else {
    for (int i = blockIdx.x*blockDim.x + threadIdx.x; i < NPAD; i += gridDim.x*blockDim.x) {
      int d = i / PD; int rem = i - d*PD;
      int g = rem / 304; int jj = rem - g*304;
      float v = 0.f;
      if (jj < NH) {
        v = d ? (bih_b[g*NH + jj] + bhh_b[g*NH + jj]) : (bih_f[g*NH + jj] + bhh_f[g*NH + jj]);
      }
      bias_sum[i] = v;
    }
  }
}

// ---------------- K1: input projection GEMM (emb16 gather) ----------------
__global__ __launch_bounds__(256) void k_inproj(
    const _Float16* __restrict__ emb16, const int* __restrict__ text, const int* __restrict__ aspect,
    const _Float16* __restrict__ Wih_frag, const float* __restrict__ bias_sum,
    const int* __restrict__ lens,
    _Float16* __restrict__ Pc, _Float16* __restrict__ Pa)
{
  const int l = threadIdx.x & 63, w = threadIdx.x >> 6;
  const int m0 = blockIdx.x * 128, n0 = blockIdx.y * 128;
  const int lrow = l & 15, lk = (l >> 4) * 8;
  __shared__ __align__(16) _Float16 Cs[128*136];

  const _Float16* ap[2];
  #pragma unroll
  for (int q = 0; q < 2; q++) {
    int r = m0 + (2*w + q)*16 + lrow;
    int tok;
    if (r < TOK_CTX) { int t = r >> 8, b = r & 255; tok = text[b*NS + t]; }
    else { int rr = r - TOK_CTX; int t = rr >> 8, b = rr & 255; tok = aspect[b*NA + t]; }
    ap[q] = emb16 + (long)tok*KP + lk;
  }
  const _Float16* bp = Wih_frag + (size_t)(n0 >> 4)*10*512 + l*8;

  f32x4 acc[2][8];
  #pragma unroll
  for (int q = 0; q < 2; q++)
    #pragma unroll
    for (int nt = 0; nt < 8; nt++) acc[q][nt] = (f32x4){0.f,0.f,0.f,0.f};

  #pragma unroll
  for (int k0 = 0; k0 < 10; k0++) {
    half8 a0 = *(const half8*)(ap[0] + k0*32);
    half8 a1 = *(const half8*)(ap[1] + k0*32);
    #pragma unroll
    for (int nt = 0; nt < 8; nt++) {
      half8 bb = *(const half8*)(bp + (size_t)(nt*10 + k0)*512);
      acc[0][nt] = __builtin_amdgcn_mfma_f32_16x16x32_f16(a0, bb, acc[0][nt], 0, 0, 0);
      acc[1][nt] = __builtin_amdgcn_mfma_f32_16x16x32_f16(a1, bb, acc[1][nt], 0, 0, 0);
    }
  }

  #pragma unroll
  for (int nt = 0; nt < 8; nt++) {
    float bias = bias_sum[n0 + nt*16 + lrow];
    #pragma unroll
    for (int q = 0; q < 2; q++) {
      int lr = (2*w + q)*16 + (l>>4)*4;
      #pragma unroll
      for (int r = 0; r < 4; r++)
        Cs[(lr + r)*136 + nt*16 + lrow] = (_Float16)(acc[q][nt][r] + bias);
    }
  }
  __syncthreads();

  const bool isCtx = (m0 < TOK_CTX);
  _Float16* __restrict__ Pdst = isCtx ? Pc : Pa;
  const int T2 = isCtx ? NS : NA;
  const int mrel = isCtx ? m0 : (m0 - TOK_CTX);
  const int tq = mrel >> 8;
  const int b_base = mrel & 255;
  const int lenoff = isCtx ? NB : 2*NB;
  const int chunk = l & 15;
  const int col = n0 + chunk*8;
  const int d = (col >= PD) ? 1 : 0;
  const int rem = col - d*PD;
  #pragma unroll
  for (int it = 0; it < 8; it++) {
    const int row = w*32 + it*4 + (l >> 4);
    const int b = b_base + row;
    int tp = tq; bool doit = true;
    if (d == 1) {
      int len = lens[lenoff + b];
      if (tq < len) tp = len - 1 - tq; else doit = false;
    }
    if (doit) {
      half8 v = *(const half8*)&Cs[row*136 + chunk*8];
      *(half8*)&Pdst[((size_t)(d*T2 + tp)*256 + b)*PD + rem] = v;
    }
  }
}

// ---------------- K2: persistent LSTM scan, wave-poll (AGENT scope) ----------
__global__ __launch_bounds__(256) void k_lstm_scan(
    const _Float16* __restrict__ Pc, const _Float16* __restrict__ Pa,
    const _Float16* __restrict__ Whh_frag, const int* __restrict__ lens,
    _Float16* __restrict__ hpadC, _Float16* __restrict__ hpadA,
    int* __restrict__ flags)   // [16*128] ints, zeroed before launch
{
  const int lin = blockIdx.x;
  const int xcd = lin & 7;
  const int kk2 = lin >> 3;        // 0..37
  const int half = kk2 / 19;
  const int js = kk2 - half*19;
  const int g  = xcd + 8*half;     // 0..15
  const int which = g >> 3;
  const int d  = (g >> 2) & 1;
  const int mg = g & 3;

  const int l = threadIdx.x & 63, w = threadIdx.x >> 6;
  const int T = which ? NA : NS;
  const _Float16* __restrict__ Pbase = which ? Pa : Pc;
  const int* __restrict__ lenp = lens + (which ? 2*NB : NB);
  _Float16* __restrict__ hpad = which ? hpadA : hpadC;
  int* __restrict__ flg = flags + g*128;   // this group's private flag region

  const int lrow = l & 15, lk = (l >> 4)*8, mrow = l >> 4;
  const int b0 = mg*64 + w*16;
  const int cbase = lk >> 4;   // 0/1
  const int koff  = lk & 8;

  // preload this block's Whh fragments into registers (40 x half8)
  half8 wf[10][4];
  #pragma unroll
  for (int k0 = 0; k0 < 10; k0++)
    #pragma unroll
    for (int gg = 0; gg < 4; gg++)
      wf[k0][gg] = *(const half8*)(Whh_frag +
          ((((size_t)(d*4 + gg)*19 + js)*10 + k0) << 9) + l*8);

  float cst[4];
  int   lenv[4];
  #pragma unroll
  for (int r = 0; r < 4; r++) { cst[r] = 0.f; lenv[r] = lenp[b0 + mrow*4 + r]; }

  for (int t = 0; t < T; t++) {
    // prefetch this step's P gates (independent of h; hides the spin)
    const size_t slab = (size_t)(d*T + t)*256;
    float pre[4][4];
    #pragma unroll
    for (int r = 0; r < 4; r++) {
      const int b = b0 + mrow*4 + r;
      const _Float16* Pr = Pbase + (slab + b)*PD + js*16 + lrow;
      pre[r][0] = (float)Pr[0];
      pre[r][1] = (float)Pr[304];
      pre[r][2] = (float)Pr[608];
      pre[r][3] = (float)Pr[912];
    }

    f32x4 accA[4], accB[4];
    #pragma unroll
    for (int gg = 0; gg < 4; gg++) {
      accA[gg] = (f32x4){0.f,0.f,0.f,0.f};
      accB[gg] = (f32x4){0.f,0.f,0.f,0.f};
    }
    float hp[4] = {0.f, 0.f, 0.f, 0.f};

    if (t > 0) {
      // wave-decoupled poll: lane 0 of each wave spins (AGENT scope -> L2,
      // sees other blocks' adds); wave proceeds on exit. h visibility is
      // structural (step-unique single-writer L2 lines).
      if (l == 0) {
        int* fp = &flg[t-1];
        while (__hip_atomic_load(fp, __ATOMIC_RELAXED, __HIP_MEMORY_SCOPE_AGENT) < 19)
          __builtin_amdgcn_s_sleep(1);
      }
      const _Float16* __restrict__ hprev = hpad + (size_t)((t-1)*2 + d)*HCH*HSL;
      #pragma unroll
      for (int r = 0; r < 4; r++)
        hp[r] = (float)hprev[(size_t)js*HSL + (b0 + mrow*4 + r)*16 + lrow];
      const _Float16* hb = hprev + (size_t)(b0 + lrow)*16 + koff;
      #pragma unroll
      for (int k0 = 0; k0 < 10; k0 += 2) {
        half8 aE = *(const half8*)(hb + (size_t)(2*k0 + cbase)*HSL);
        half8 aO = *(const half8*)(hb + (size_t)(2*(k0+1) + cbase)*HSL);
        #pragma unroll
        for (int gg = 0; gg < 4; gg++) {
          accA[gg] = __builtin_amdgcn_mfma_f32_16x16x32_f16(aE, wf[k0][gg],   accA[gg], 0, 0, 0);
          accB[gg] = __builtin_amdgcn_mfma_f32_16x16x32_f16(aO, wf[k0+1][gg], accB[gg], 0, 0, 0);
        }
      }
    }

    // pointwise: 4 cells per thread; write h2 to this step's unique slab
    _Float16* __restrict__ hw = hpad + (size_t)(t*2 + d)*HCH*HSL + (size_t)js*HSL;
    #pragma unroll
    for (int r = 0; r < 4; r++) {
      const int b = b0 + mrow*4 + r;
      float gi = (accA[0][r] + accB[0][r]) + pre[r][0];
      float gf = (accA[1][r] + accB[1][r]) + pre[r][1];
      float gg2 = (accA[2][r] + accB[2][r]) + pre[r][2];
      float go = (accA[3][r] + accB[3][r]) + pre[r][3];
      float si = 1.f/(1.f + __expf(-gi));
      float sf = 1.f/(1.f + __expf(-gf));
      float so = 1.f/(1.f + __expf(-go));
      float cn = sf*cst[r] + si*fast_tanh(gg2);
      float hn = so*fast_tanh(cn);
      bool mt = t < lenv[r];
      float h2 = mt ? hn : hp[r];
      cst[r] = mt ? cn : cst[r];
      hw[(size_t)b*16 + lrow] = (_Float16)h2;
    }

    __syncthreads();   // drains all waves' h stores to L2 before the add
    if (threadIdx.x == 0)
      __hip_atomic_fetch_add(&flg[t], 1,
                             __ATOMIC_RELAXED, __HIP_MEMORY_SCOPE_AGENT);
  }
}

// ---------------- K3: fused combine + position weight + transpose + c_avg ----
__global__ __launch_bounds__(256) void k_ctx_fused(
    const _Float16* __restrict__ hpadC, const int* __restrict__ lens,
    _Float16* __restrict__ ctx, _Float16* __restrict__ ctxT, float* __restrict__ c_avg)
{
  const int b = blockIdx.x, tid = threadIdx.x;
  __shared__ float wgt_s[128];
  __shared__ int   tbv[128];
  __shared__ _Float16 tl[128][62];
  const int cl = lens[NB + b];
  if (tid < 128) {
    const int ll = lens[b], al = lens[2*NB + b];
    float clf = (float)cl, llf = (float)ll, alf = (float)al, tf = (float)tid;
    float denom = clf - alf + 1.f;
    float wgt = (tf < llf) ? (1.f - (llf - tf)/denom)
              : (tf < llf + alf) ? 0.f
              : (tf < clf) ? (1.f - (tf - llf - alf + 1.f)/denom) : 0.f;
    wgt_s[tid] = wgt;
    int tb0 = cl - 1 - tid; tbv[tid] = tb0 < 0 ? 0 : (tb0 > NS-1 ? NS-1 : tb0);
  }
  __syncthreads();
  const float clinv = 1.f / (float)cl;
  for (int c10 = 0; c10 < 10; c10++) {
    const int j0 = c10*60;
    for (int idx = tid; idx < 128*60; idx += 256) {
      int s = idx / 60, jc = idx - s*60;
      int j = j0 + jc;
      float v;
      if (j < NH) {
        int c = j >> 4, ww = j & 15;
        v = (float)hpadC[(((size_t)(s*2 + 0)*HCH + c)*256 + b)*16 + ww];
      } else {
        int j2 = j - NH; int c = j2 >> 4, ww = j2 & 15;
        v = (float)hpadC[(((size_t)(tbv[s]*2 + 1)*HCH + c)*256 + b)*16 + ww];
      }
      v *= wgt_s[s];
      tl[s][jc] = (_Float16)v;
      ctx[((size_t)b*NS + s)*600 + j] = (_Float16)v;
    }
    __syncthreads();
    for (int idx = tid; idx < 60*128; idx += 256) {
      int jc = idx >> 7, s = idx & 127;
      ctxT[((size_t)b*600 + j0 + jc)*NS + s] = tl[s][jc];
    }
    if (tid < 60) {
      float sum = 0.f;
      for (int s = 0; s < 128; s++) sum += (float)tl[s][tid];
      c_avg[(size_t)b*600 + j0 + tid] = sum * clinv;
    }
    __syncthreads();
  }
}

// ---------------- K4: aspect combine + a_avg -> aspc[b][a][600] ----------------
__global__ __launch_bounds__(320) void k_combine_asp(
    const _Float16* __restrict__ hpadA, const int* __restrict__ lens,
    _Float16* __restrict__ aspc, float* __restrict__ a_avg)
{
  int b = blockIdx.x, tid = threadIdx.x;
  if (tid >= NH) return;
  int al = lens[2*NB + b];
  const float alinv = 1.f / (float)al;
  const int c = tid >> 4, ww = tid & 15;
  float sumF = 0.f, sumB = 0.f;
  for (int a = 0; a < NA; a++) {
    float vf = (a < al) ? (float)hpadA[(((size_t)(a*2 + 0)*HCH + c)*256 + b)*16 + ww] : 0.f;
    int tb0 = al - 1 - a; int tb = tb0 < 0 ? 0 : (tb0 > NA-1 ? NA-1 : tb0);
    float vb = (a < al) ? (float)hpadA[(((size_t)(tb*2 + 1)*HCH + c)*256 + b)*16 + ww] : 0.f;
    aspc[((size_t)b*NA + a)*600 + tid]      = (_Float16)vf;
    aspc[((size_t)b*NA + a)*600 + NH + tid] = (_Float16)vb;
    sumF += vf; sumB += vb;
  }
  a_avg[(size_t)b*600 + tid]      = sumF * alinv;
  a_avg[(size_t)b*600 + NH + tid] = sumB * alinv;
}

// ---------------- K6: s1 = a_avg@w1 ; s2 = c_avg@w2 ----------------
__global__ void k_sw(const float* __restrict__ a_avg, const float* __restrict__ c_avg,
                     const float* __restrict__ w1, const float* __restrict__ w2,
                     float* __restrict__ s1, float* __restrict__ s2) {
  __shared__ float src[8][600];
  int bg = blockIdx.x * 8, which = blockIdx.y, tid = threadIdx.x;
  const float* sp = which ? c_avg : a_avg;
  const float* w  = which ? w2 : w1;
  float* outp     = which ? s2 : s1;
  for (int u = tid; u < 8*600; u += 640) {
    int q = u / 600, dd = u - q*600;
    src[q][dd] = sp[(long)(bg + q)*600 + dd];
  }
  __syncthreads();
  int j = tid;
  if (j >= 600) return;
  float acc[8] = {0,0,0,0,0,0,0,0};
  for (int dd = 0; dd < 600; dd++) {
    float wvv = w[dd*600 + j];
    #pragma unroll
    for (int q = 0; q < 8; q++) acc[q] += src[q][dd] * wvv;
  }
  #pragma unroll
  for (int q = 0; q < 8; q++) outp[(long)(bg + q)*600 + j] = acc[q];
}

// ---------------- K7: alpha1 + mca ----------------
__global__ __launch_bounds__(128) void k_att_ctx(const _Float16* __restrict__ ctxT,
    const _Float16* __restrict__ ctx, const float* __restrict__ s1, float* __restrict__ mca) {
  int b = blockIdx.x, tid = threadIdx.x;
  __shared__ float sv[600];
  __shared__ float red[128];
  __shared__ float mx, sm;
  for (int u = tid; u < 600; u += 128) sv[u] = s1[(long)b*600 + u];
  __syncthreads();
  float sc = 0.f;
  for (int dd = 0; dd < 600; dd++) sc += sv[dd] * (float)ctxT[((long)b*600 + dd)*NS + tid];
  red[tid] = sc; __syncthreads();
  if (tid == 0) { float m = -1e30f; for (int i = 0; i < 128; i++) m = fmaxf(m, red[i]); mx = m; }
  __syncthreads();
  float e = __expf(sc - mx);
  red[tid] = e; __syncthreads();
  if (tid == 0) { float s = 0.f; for (int i = 0; i < 128; i++) s += red[i]; sm = s; }
  __syncthreads();
  float alpha = e / sm;
  red[tid] = alpha; __syncthreads();
  for (int i = 0; i < 5; i++) {
    int j = tid + i*128;
    if (j < 600) {
      float acc = 0.f;
      for (int s2 = 0; s2 < NS; s2++) acc += red[s2] * (float)ctx[((long)b*NS + s2)*600 + j];
      mca[(long)b*600 + j] = acc;
    }
  }
}

// ---------------- K8: alpha2 + mcc ----------------
__global__ void k_att_asp(const _Float16* __restrict__ aspc, const float* __restrict__ s2,
                          float* __restrict__ mcc) {
  int b = blockIdx.x, tid = threadIdx.x, wvv = tid >> 6, lane = tid & 63;
  __shared__ float sv[600];
  __shared__ float sc8[8];
  for (int u = tid; u < 600; u += 512) sv[u] = s2[(long)b*600 + u];
  __syncthreads();
  float p = 0.f;
  for (int dd = lane; dd < 600; dd += 64) p += sv[dd] * (float)aspc[((long)b*NA + wvv)*600 + dd];
  #pragma unroll
  for (int off = 32; off; off >>= 1) p += __shfl_down(p, off);
  if (lane == 0) sc8[wvv] = p;
  __syncthreads();
  float m = -1e30f;
  #pragma unroll
  for (int a = 0; a < 8; a++) m = fmaxf(m, sc8[a]);
  float es[8]; float ssum = 0.f;
  #pragma unroll
  for (int a = 0; a < 8; a++) { es[a] = __expf(sc8[a] - m); ssum += es[a]; }
  float inv = 1.f / ssum;
  for (int i = 0; i < 2; i++) {
    int j = tid + i*512;
    if (j < 600) {
      float acc = 0.f;
      #pragma unroll
      for (int a = 0; a < 8; a++) acc += es[a]*inv * (float)aspc[((long)b*NA + a)*600 + j];
      mcc[(long)b*600 + j] = acc;
    }
  }
}

// ---------------- K9: u tensor -> mfa, mfc ----------------
__global__ __launch_bounds__(128) void k_u(const _Float16* __restrict__ ctxT, const _Float16* __restrict__ ctx,
    const _Float16* __restrict__ aspc, const float* __restrict__ fc1_w, const float* __restrict__ fc1_b,
    float* __restrict__ mfa, float* __restrict__ mfc) {
  int b = blockIdx.x, tid = threadIdx.x;   // tid == s
  __shared__ __align__(16) float aspl[4800];
  __shared__ float ua8[8];
  __shared__ float red[128];
  __shared__ float qa8[8];
  __shared__ float mx1, sm1;
  __shared__ float pal[128][8];
  for (int u = tid; u < 4800; u += 128) {
    int a = u / 600, dd = u - a*600;
    aspl[dd*8 + a] = (float)aspc[((long)b*NA + a)*600 + dd];
  }
  __syncthreads();
  const float* wc = fc1_w;
  const float* wa = fc1_w + 600;
  const float* wm = fc1_w + 1200;
  {
    int wvv = tid >> 6, lane = tid & 63;
    for (int q = 0; q < 4; q++) {
      int a = wvv*4 + q;
      float p = 0.f;
      for (int dd = lane; dd < 600; dd += 64) p += wa[dd] * aspl[dd*8 + a];
      #pragma unroll
      for (int off = 32; off; off >>= 1) p += __shfl_down(p, off);
      if (lane == 0) ua8[a] = p;
    }
  }
  __syncthreads();
  float x8[8] = {0,0,0,0,0,0,0,0};
  float uc = 0.f;
  for (int dd = 0; dd < 600; dd++) {
    float cv = (float)ctxT[((long)b*600 + dd)*NS + tid];
    uc += cv * wc[dd];
    float cm = cv * wm[dd];
    float4 a03 = *(const float4*)&aspl[dd*8];
    float4 a47 = *(const float4*)&aspl[dd*8 + 4];
    x8[0] += cm*a03.x; x8[1] += cm*a03.y; x8[2] += cm*a03.z; x8[3] += cm*a03.w;
    x8[4] += cm*a47.x; x8[5] += cm*a47.y; x8[6] += cm*a47.z; x8[7] += cm*a47.w;
  }
  float fb = fc1_b[0];
  float u8v[8]; float umax = -1e30f;
  #pragma unroll
  for (int a = 0; a < 8; a++) { u8v[a] = uc + ua8[a] + x8[a] + fb; umax = fmaxf(umax, u8v[a]); }
  float pa[8]; float psum = 0.f;
  #pragma unroll
  for (int a = 0; a < 8; a++) { pa[a] = __expf(u8v[a] - umax); psum += pa[a]; }
  float pin = 1.f / psum;
  #pragma unroll
  for (int a = 0; a < 8; a++) pal[tid][a] = pa[a] * pin;
  red[tid] = umax;
  __syncthreads();
  if (tid == 0) { float m = -1e30f; for (int i = 0; i < 128; i++) m = fmaxf(m, red[i]); mx1 = m; }
  if (tid < 8) { float s = 0.f; for (int i = 0; i < 128; i++) s += pal[i][tid]; qa8[tid] = s * (1.f/128.f); }
  __syncthreads();
  float e = __expf(umax - mx1);
  red[tid] = e;
  __syncthreads();
  if (tid == 0) { float s = 0.f; for (int i = 0; i < 128; i++) s += red[i]; sm1 = s; }
  __syncthreads();
  float alpha = e / sm1;
  red[tid] = alpha;
  __syncthreads();
  for (int i = 0; i < 5; i++) {
    int j = tid + i*128;
    if (j < 600) {
      float am = 0.f;
      for (int s2 = 0; s2 < NS; s2++) am += red[s2] * (float)ctx[((long)b*NS + s2)*600 + j];
      float4 a03 = *(const float4*)&aspl[j*8];
      float4 a47 = *(const float4*)&aspl[j*8 + 4];
      mfa[(long)b*600 + j] = am;
      mfc[(long)b*600 + j] = qa8[0]*a03.x + qa8[1]*a03.y + qa8[2]*a03.z + qa8[3]*a03.w
                           + qa8[4]*a47.x + qa8[5]*a47.y + qa8[6]*a47.z + qa8[7]*a47.w;
    }
  }
}

// ---------------- K10: final FC + softmax ----------------
__global__ void k_final(const float* __restrict__ mca, const float* __restrict__ mcc,
                        const float* __restrict__ mfa, const float* __restrict__ mfc,
                        const float* __restrict__ fc2_w, const float* __restrict__ fc2_b,
                        float* __restrict__ out) {
  int b = blockIdx.x, tid = threadIdx.x, c = tid >> 6, lane = tid & 63;
  __shared__ float lg[3];
  float p = 0.f;
  for (int u = lane; u < 2400; u += 64) {
    int piece = u / 600;
    int jj = u - piece*600;
    const float* src = (piece == 0) ? mca : (piece == 1) ? mcc : (piece == 2) ? mfa : mfc;
    p += src[(long)b*600 + jj] * fc2_w[c*2400 + u];
  }
  #pragma unroll
  for (int off = 32; off; off >>= 1) p += __shfl_down(p, off);
  if (lane == 0) lg[c] = p + fc2_b[c];
  __syncthreads();
  if (tid == 0) {
    float m = fmaxf(lg[0], fmaxf(lg[1], lg[2]));
    float e0 = __expf(lg[0]-m), e1 = __expf(lg[1]-m), e2 = __expf(lg[2]-m);
    float s = e0 + e1 + e2;
    out[b*3 + 0] = e0/s; out[b*3 + 1] = e1/s; out[b*3 + 2] = e2/s;
  }
}

// ---------------- host ----------------
extern "C" void kernel_launch(void* const* d_in, const int* in_sizes, int n_in,
                              void* d_out, int out_size, void* d_ws, size_t ws_size,
                              hipStream_t stream)
{
  const int*   text    = (const int*)d_in[0];
  const int*   aspect  = (const int*)d_in[1];
  const int*   left    = (const int*)d_in[2];
  const float* emb     = (const float*)d_in[3];
  const float* Wih_f   = (const float*)d_in[4];
  const float* Whh_f   = (const float*)d_in[5];
  const float* bih_f   = (const float*)d_in[6];
  const float* bhh_f   = (const float*)d_in[7];
  const float* Wih_b   = (const float*)d_in[8];
  const float* Whh_b   = (const float*)d_in[9];
  const float* bih_b   = (const float*)d_in[10];
  const float* bhh_b   = (const float*)d_in[11];
  const float* w1      = (const float*)d_in[12];
  const float* w2      = (const float*)d_in[13];
  const float* fc1_w   = (const float*)d_in[14];
  const float* fc1_b   = (const float*)d_in[15];
  const float* fc2_w   = (const float*)d_in[16];
  const float* fc2_b   = (const float*)d_in[17];
  float* out = (float*)d_out;

  char* base = (char*)d_ws;
  size_t off = 0;
  auto alloc = [&](size_t bytes) -> void* {
    void* p = base + off;
    off = (off + bytes + 255) & ~(size_t)255;
    return p;
  };
  int*      lens     = (int*)     alloc(3 * NB * sizeof(int));
  int*      flags    = (int*)     alloc((size_t)16*128 * sizeof(int));            // 8 KB padded
  float*    bias_sum = (float*)   alloc(NPAD * sizeof(float));
  _Float16* Wih_frag = (_Float16*)alloc((size_t)152*10*512 * sizeof(_Float16));   // 1.56 MB
  _Float16* Whh_frag = (_Float16*)alloc((size_t)152*10*512 * sizeof(_Float16));   // 1.56 MB
  float*    c_avg    = (float*)   alloc((size_t)NB*600 * sizeof(float));
  float*    a_avg    = (float*)   alloc((size_t)NB*600 * sizeof(float));
  float*    s1       = (float*)   alloc((size_t)NB*600 * sizeof(float));
  float*    s2       = (float*)   alloc((size_t)NB*600 * sizeof(float));
  float*    mca      = (float*)   alloc((size_t)NB*600 * sizeof(float));
  float*    mcc      = (float*)   alloc((size_t)NB*600 * sizeof(float));
  float*    mfa      = (float*)   alloc((size_t)NB*600 * sizeof(float));
  float*    mfc      = (float*)   alloc((size_t)NB*600 * sizeof(float));
  _Float16* hpadC    = (_Float16*)alloc((size_t)NS*2*HCH*HSL * sizeof(_Float16)); // 41.9 MB
  _Float16* hpadA    = (_Float16*)alloc((size_t)NA*2*HCH*HSL * sizeof(_Float16)); // 2.62 MB
  // emb16 (20.5 MB) overlays hpadC: used only by cvt_emb+inproj (before scan)
  _Float16* emb16    = hpadC;
  // BIG region: Pc (159.4 MB) + Pa (10 MB); ctx/ctxT/aspc (81 MB) overlay Pc later
  _Float16* Pc = (_Float16*)alloc((size_t)2*NS*NB*PD * sizeof(_Float16));
  _Float16* Pa = (_Float16*)alloc((size_t)2*NA*NB*PD * sizeof(_Float16));
  _Float16* ctx  = Pc;
  _Float16* ctxT = ctx  + (size_t)NB*NS*600;
  _Float16* aspc = ctxT + (size_t)NB*NS*600;
  if (ws_size < off) return;  // clean zero-output signal instead of OOB

  k_lengths<<<1, 256, 0, stream>>>(text, aspect, left, lens);
  k_cvt_emb<<<2048, 256, 0, stream>>>(emb, emb16);
  k_cvt_w<<<dim3(512, 3), 256, 0, stream>>>(Wih_f, Wih_b, Whh_f, Whh_b,
                                            bih_f, bhh_f, bih_b, bhh_b,
                                            Wih_frag, Whh_frag, bias_sum);
  k_inproj<<<dim3(272, 19), 256, 0, stream>>>(emb16, text, aspect, Wih_frag, bias_sum,
                                              lens, Pc, Pa);

  hipMemsetAsync(flags, 0, (size_t)16*128 * sizeof(int), stream);
  k_lstm_scan<<<304, 256, 0, stream>>>(Pc, Pa, Whh_frag, lens, hpadC, hpadA, flags);

  k_ctx_fused<<<256, 256, 0, stream>>>(hpadC, lens, ctx, ctxT, c_avg);
  k_combine_asp<<<256, 320, 0, stream>>>(hpadA, lens, aspc, a_avg);
  k_sw<<<dim3(32, 2), 640, 0, stream>>>(a_avg, c_avg, w1, w2, s1, s2);
  k_att_ctx<<<256, 128, 0, stream>>>(ctxT, ctx, s1, mca);
  k_att_asp<<<256, 512, 0, stream>>>(aspc, s2, mcc);
  k_u<<<256, 128, 0, stream>>>(ctxT, ctx, aspc, fc1_w, fc1_b, mfa, mfc);
  k_final<<<256, 192, 0, stream>>>(mca, mcc, mfa, mfc, fc2_w, fc2_b, out);
}

// Round 22
// 1023.991 us; speedup vs baseline: 1.1886x; 1.0657x over previous
//
#include <hip/hip_runtime.h>
#include <hip/hip_bf16.h>
#include <hip/hip_fp16.h>

// ---------------------------------------------------------------------------
// MGAN forward. fp16 MFMA; persistent LSTM scan, XCD-colocated sync groups.
//   B=256 S=128 A=8 L=32 D=H=300 NC=3 VOCAB=32000
// MFMA 16x16x32_f16 fragment scheme (validated rounds 2-21).
// P scan-order: Pscan[d][t'][b][1216]. Both weights fragment-major.
// Scan: ONE launch, 304 blocks, XCD swizzle; r19 protocol (best measured:
// scan ~516us): wave-poll consumers (RELAXED/AGENT, quorum 19), block-drain
// producers (__syncthreads + single thread0 relaxed add to padded per-group
// flag region flags[g*128+t]).
// r22: tail kernels K7/K8/K9 (att_ctx, att_asp, u) merged into ONE dispatch
// grid(256,3) x 128thr — independent kernels run concurrently (sum -> max),
// K8 rewritten for 128 threads (2 waves x 4 aspects, same summation order).
// ---------------------------------------------------------------------------

#define NB   256
#define NS   128
#define NA   8
#define NL   32
#define ND   300
#define NH   300
#define NPAD  2432      // 2*4*304 (bias/Wih padded n-space)
#define KP    320
#define TOK_CTX 32768
#define PD    1216      // per-dir gate row: 4*304
#define HCH   20        // h chunks per (t,d): 20*16 = 320 k-range
#define HSL   4096      // 256*16 halves per chunk

typedef _Float16 half8 __attribute__((ext_vector_type(8)));
typedef float    f32x4 __attribute__((ext_vector_type(4)));

__device__ __forceinline__ float fast_tanh(float x) {
  float e = __expf(-2.f * x);          // inf-safe: e=inf -> -1, e=0 -> +1
  return 2.f / (1.f + e) - 1.f;
}

// ---------------- K0: sequence lengths ----------------
__global__ void k_lengths(const int* __restrict__ text, const int* __restrict__ aspect,
                          const int* __restrict__ left, int* __restrict__ lens) {
  int b = threadIdx.x;
  if (b >= NB) return;
  int ll = 0; for (int i = 0; i < NL; i++) ll += (left[b*NL + i] != 0);
  int cl = 0; for (int i = 0; i < NS; i++) cl += (text[b*NS + i] != 0);
  int al = 0; for (int i = 0; i < NA; i++) al += (aspect[b*NA + i] != 0);
  lens[b] = ll; lens[NB + b] = cl; lens[2*NB + b] = al;
}

// ---------------- K0b: emb f32 -> fp16, K padded 300->320 ----------------
__global__ void k_cvt_emb(const float* __restrict__ emb, _Float16* __restrict__ emb16) {
  const long N = (long)32000 * KP;
  for (long i = (long)blockIdx.x*blockDim.x + threadIdx.x; i < N; i += (long)gridDim.x*blockDim.x) {
    long v = i / KP; int k = (int)(i - v*KP);
    emb16[i] = (k < ND) ? (_Float16)emb[v*ND + k] : (_Float16)0.f;
  }
}

// ---------------- converter: Wih_frag / Whh_frag / bias ----------------
__global__ void k_cvt_w(const float* __restrict__ Wih_f, const float* __restrict__ Wih_b,
                        const float* __restrict__ Whh_f, const float* __restrict__ Whh_b,
                        const float* __restrict__ bih_f, const float* __restrict__ bhh_f,
                        const float* __restrict__ bih_b, const float* __restrict__ bhh_b,
                        _Float16* __restrict__ Wih_frag, _Float16* __restrict__ Whh_frag,
                        float* __restrict__ bias_sum) {
  int y = blockIdx.y;
  if (y < 2) {
    const float* sf = y ? Whh_f : Wih_f;
    const float* sb = y ? Whh_b : Wih_b;
    _Float16* dst = y ? Whh_frag : Wih_frag;
    const long N = (long)152*10*512;   // 778240
    for (long i = (long)blockIdx.x*blockDim.x + threadIdx.x; i < N; i += (long)gridDim.x*blockDim.x) {
      long q = i >> 9; int r512 = (int)(i & 511);
      int l = r512 >> 3, e = r512 & 7;
      int k0 = (int)(q % 10);
      int ntile = (int)(q / 10);
      int n = ntile*16 + (l & 15);
      int k = k0*32 + (l >> 4)*8 + e;
      int d = n / PD; int rem = n - d*PD;
      int g = rem / 304; int jj = rem - g*304;
      float v = 0.f;
      if (jj < NH && k < NH) {
        const float* src = d ? sb : sf;
        v = src[(long)(g*NH + jj)*NH + k];
      }
      dst[i] = (_Float16)v;
    }
  } else {
    for (int i = blockIdx.x*blockDim.x + threadIdx.x; i < NPAD; i += gridDim.x*blockDim.x) {
      int d = i / PD; int rem = i - d*PD;
      int g = rem / 304; int jj = rem - g*304;
      float v = 0.f;
      if (jj < NH) {
        v = d ? (bih_b[g*NH + jj] + bhh_b[g*NH + jj]) : (bih_f[g*NH + jj] + bhh_f[g*NH + jj]);
      }
      bias_sum[i] = v;
    }
  }
}

// ---------------- K1: input projection GEMM (emb16 gather) ----------------
__global__ __launch_bounds__(256) void k_inproj(
    const _Float16* __restrict__ emb16, const int* __restrict__ text, const int* __restrict__ aspect,
    const _Float16* __restrict__ Wih_frag, const float* __restrict__ bias_sum,
    const int* __restrict__ lens,
    _Float16* __restrict__ Pc, _Float16* __restrict__ Pa)
{
  const int l = threadIdx.x & 63, w = threadIdx.x >> 6;
  const int m0 = blockIdx.x * 128, n0 = blockIdx.y * 128;
  const int lrow = l & 15, lk = (l >> 4) * 8;
  __shared__ __align__(16) _Float16 Cs[128*136];

  const _Float16* ap[2];
  #pragma unroll
  for (int q = 0; q < 2; q++) {
    int r = m0 + (2*w + q)*16 + lrow;
    int tok;
    if (r < TOK_CTX) { int t = r >> 8, b = r & 255; tok = text[b*NS + t]; }
    else { int rr = r - TOK_CTX; int t = rr >> 8, b = rr & 255; tok = aspect[b*NA + t]; }
    ap[q] = emb16 + (long)tok*KP + lk;
  }
  const _Float16* bp = Wih_frag + (size_t)(n0 >> 4)*10*512 + l*8;

  f32x4 acc[2][8];
  #pragma unroll
  for (int q = 0; q < 2; q++)
    #pragma unroll
    for (int nt = 0; nt < 8; nt++) acc[q][nt] = (f32x4){0.f,0.f,0.f,0.f};

  #pragma unroll
  for (int k0 = 0; k0 < 10; k0++) {
    half8 a0 = *(const half8*)(ap[0] + k0*32);
    half8 a1 = *(const half8*)(ap[1] + k0*32);
    #pragma unroll
    for (int nt = 0; nt < 8; nt++) {
      half8 bb = *(const half8*)(bp + (size_t)(nt*10 + k0)*512);
      acc[0][nt] = __builtin_amdgcn_mfma_f32_16x16x32_f16(a0, bb, acc[0][nt], 0, 0, 0);
      acc[1][nt] = __builtin_amdgcn_mfma_f32_16x16x32_f16(a1, bb, acc[1][nt], 0, 0, 0);
    }
  }

  #pragma unroll
  for (int nt = 0; nt < 8; nt++) {
    float bias = bias_sum[n0 + nt*16 + lrow];
    #pragma unroll
    for (int q = 0; q < 2; q++) {
      int lr = (2*w + q)*16 + (l>>4)*4;
      #pragma unroll
      for (int r = 0; r < 4; r++)
        Cs[(lr + r)*136 + nt*16 + lrow] = (_Float16)(acc[q][nt][r] + bias);
    }
  }
  __syncthreads();

  const bool isCtx = (m0 < TOK_CTX);
  _Float16* __restrict__ Pdst = isCtx ? Pc : Pa;
  const int T2 = isCtx ? NS : NA;
  const int mrel = isCtx ? m0 : (m0 - TOK_CTX);
  const int tq = mrel >> 8;
  const int b_base = mrel & 255;
  const int lenoff = isCtx ? NB : 2*NB;
  const int chunk = l & 15;
  const int col = n0 + chunk*8;
  const int d = (col >= PD) ? 1 : 0;
  const int rem = col - d*PD;
  #pragma unroll
  for (int it = 0; it < 8; it++) {
    const int row = w*32 + it*4 + (l >> 4);
    const int b = b_base + row;
    int tp = tq; bool doit = true;
    if (d == 1) {
      int len = lens[lenoff + b];
      if (tq < len) tp = len - 1 - tq; else doit = false;
    }
    if (doit) {
      half8 v = *(const half8*)&Cs[row*136 + chunk*8];
      *(half8*)&Pdst[((size_t)(d*T2 + tp)*256 + b)*PD + rem] = v;
    }
  }
}

// ---------------- K2: persistent LSTM scan, wave-poll (AGENT scope) ----------
__global__ __launch_bounds__(256) void k_lstm_scan(
    const _Float16* __restrict__ Pc, const _Float16* __restrict__ Pa,
    const _Float16* __restrict__ Whh_frag, const int* __restrict__ lens,
    _Float16* __restrict__ hpadC, _Float16* __restrict__ hpadA,
    int* __restrict__ flags)   // [16*128] ints, zeroed before launch
{
  const int lin = blockIdx.x;
  const int xcd = lin & 7;
  const int kk2 = lin >> 3;        // 0..37
  const int half = kk2 / 19;
  const int js = kk2 - half*19;
  const int g  = xcd + 8*half;     // 0..15
  const int which = g >> 3;
  const int d  = (g >> 2) & 1;
  const int mg = g & 3;

  const int l = threadIdx.x & 63, w = threadIdx.x >> 6;
  const int T = which ? NA : NS;
  const _Float16* __restrict__ Pbase = which ? Pa : Pc;
  const int* __restrict__ lenp = lens + (which ? 2*NB : NB);
  _Float16* __restrict__ hpad = which ? hpadA : hpadC;
  int* __restrict__ flg = flags + g*128;   // this group's private flag region

  const int lrow = l & 15, lk = (l >> 4)*8, mrow = l >> 4;
  const int b0 = mg*64 + w*16;
  const int cbase = lk >> 4;   // 0/1
  const int koff  = lk & 8;

  // preload this block's Whh fragments into registers (40 x half8)
  half8 wf[10][4];
  #pragma unroll
  for (int k0 = 0; k0 < 10; k0++)
    #pragma unroll
    for (int gg = 0; gg < 4; gg++)
      wf[k0][gg] = *(const half8*)(Whh_frag +
          ((((size_t)(d*4 + gg)*19 + js)*10 + k0) << 9) + l*8);

  float cst[4];
  int   lenv[4];
  #pragma unroll
  for (int r = 0; r < 4; r++) { cst[r] = 0.f; lenv[r] = lenp[b0 + mrow*4 + r]; }

  for (int t = 0; t < T; t++) {
    // prefetch this step's P gates (independent of h; hides the spin)
    const size_t slab = (size_t)(d*T + t)*256;
    float pre[4][4];
    #pragma unroll
    for (int r = 0; r < 4; r++) {
      const int b = b0 + mrow*4 + r;
      const _Float16* Pr = Pbase + (slab + b)*PD + js*16 + lrow;
      pre[r][0] = (float)Pr[0];
      pre[r][1] = (float)Pr[304];
      pre[r][2] = (float)Pr[608];
      pre[r][3] = (float)Pr[912];
    }

    f32x4 accA[4], accB[4];
    #pragma unroll
    for (int gg = 0; gg < 4; gg++) {
      accA[gg] = (f32x4){0.f,0.f,0.f,0.f};
      accB[gg] = (f32x4){0.f,0.f,0.f,0.f};
    }
    float hp[4] = {0.f, 0.f, 0.f, 0.f};

    if (t > 0) {
      // wave-decoupled poll: lane 0 of each wave spins (AGENT scope -> L2,
      // sees other blocks' adds); wave proceeds on exit. h visibility is
      // structural (step-unique single-writer L2 lines).
      if (l == 0) {
        int* fp = &flg[t-1];
        while (__hip_atomic_load(fp, __ATOMIC_RELAXED, __HIP_MEMORY_SCOPE_AGENT) < 19)
          __builtin_amdgcn_s_sleep(1);
      }
      const _Float16* __restrict__ hprev = hpad + (size_t)((t-1)*2 + d)*HCH*HSL;
      #pragma unroll
      for (int r = 0; r < 4; r++)
        hp[r] = (float)hprev[(size_t)js*HSL + (b0 + mrow*4 + r)*16 + lrow];
      const _Float16* hb = hprev + (size_t)(b0 + lrow)*16 + koff;
      #pragma unroll
      for (int k0 = 0; k0 < 10; k0 += 2) {
        half8 aE = *(const half8*)(hb + (size_t)(2*k0 + cbase)*HSL);
        half8 aO = *(const half8*)(hb + (size_t)(2*(k0+1) + cbase)*HSL);
        #pragma unroll
        for (int gg = 0; gg < 4; gg++) {
          accA[gg] = __builtin_amdgcn_mfma_f32_16x16x32_f16(aE, wf[k0][gg],   accA[gg], 0, 0, 0);
          accB[gg] = __builtin_amdgcn_mfma_f32_16x16x32_f16(aO, wf[k0+1][gg], accB[gg], 0, 0, 0);
        }
      }
    }

    // pointwise: 4 cells per thread; write h2 to this step's unique slab
    _Float16* __restrict__ hw = hpad + (size_t)(t*2 + d)*HCH*HSL + (size_t)js*HSL;
    #pragma unroll
    for (int r = 0; r < 4; r++) {
      const int b = b0 + mrow*4 + r;
      float gi = (accA[0][r] + accB[0][r]) + pre[r][0];
      float gf = (accA[1][r] + accB[1][r]) + pre[r][1];
      float gg2 = (accA[2][r] + accB[2][r]) + pre[r][2];
      float go = (accA[3][r] + accB[3][r]) + pre[r][3];
      float si = 1.f/(1.f + __expf(-gi));
      float sf = 1.f/(1.f + __expf(-gf));
      float so = 1.f/(1.f + __expf(-go));
      float cn = sf*cst[r] + si*fast_tanh(gg2);
      float hn = so*fast_tanh(cn);
      bool mt = t < lenv[r];
      float h2 = mt ? hn : hp[r];
      cst[r] = mt ? cn : cst[r];
      hw[(size_t)b*16 + lrow] = (_Float16)h2;
    }

    __syncthreads();   // drains all waves' h stores to L2 before the add
    if (threadIdx.x == 0)
      __hip_atomic_fetch_add(&flg[t], 1,
                             __ATOMIC_RELAXED, __HIP_MEMORY_SCOPE_AGENT);
  }
}

// ---------------- K3: fused combine + position weight + transpose + c_avg ----
__global__ __launch_bounds__(256) void k_ctx_fused(
    const _Float16* __restrict__ hpadC, const int* __restrict__ lens,
    _Float16* __restrict__ ctx, _Float16* __restrict__ ctxT, float* __restrict__ c_avg)
{
  const int b = blockIdx.x, tid = threadIdx.x;
  __shared__ float wgt_s[128];
  __shared__ int   tbv[128];
  __shared__ _Float16 tl[128][62];
  const int cl = lens[NB + b];
  if (tid < 128) {
    const int ll = lens[b], al = lens[2*NB + b];
    float clf = (float)cl, llf = (float)ll, alf = (float)al, tf = (float)tid;
    float denom = clf - alf + 1.f;
    float wgt = (tf < llf) ? (1.f - (llf - tf)/denom)
              : (tf < llf + alf) ? 0.f
              : (tf < clf) ? (1.f - (tf - llf - alf + 1.f)/denom) : 0.f;
    wgt_s[tid] = wgt;
    int tb0 = cl - 1 - tid; tbv[tid] = tb0 < 0 ? 0 : (tb0 > NS-1 ? NS-1 : tb0);
  }
  __syncthreads();
  const float clinv = 1.f / (float)cl;
  for (int c10 = 0; c10 < 10; c10++) {
    const int j0 = c10*60;
    for (int idx = tid; idx < 128*60; idx += 256) {
      int s = idx / 60, jc = idx - s*60;
      int j = j0 + jc;
      float v;
      if (j < NH) {
        int c = j >> 4, ww = j & 15;
        v = (float)hpadC[(((size_t)(s*2 + 0)*HCH + c)*256 + b)*16 + ww];
      } else {
        int j2 = j - NH; int c = j2 >> 4, ww = j2 & 15;
        v = (float)hpadC[(((size_t)(tbv[s]*2 + 1)*HCH + c)*256 + b)*16 + ww];
      }
      v *= wgt_s[s];
      tl[s][jc] = (_Float16)v;
      ctx[((size_t)b*NS + s)*600 + j] = (_Float16)v;
    }
    __syncthreads();
    for (int idx = tid; idx < 60*128; idx += 256) {
      int jc = idx >> 7, s = idx & 127;
      ctxT[((size_t)b*600 + j0 + jc)*NS + s] = tl[s][jc];
    }
    if (tid < 60) {
      float sum = 0.f;
      for (int s = 0; s < 128; s++) sum += (float)tl[s][tid];
      c_avg[(size_t)b*600 + j0 + tid] = sum * clinv;
    }
    __syncthreads();
  }
}

// ---------------- K4: aspect combine + a_avg -> aspc[b][a][600] ----------------
__global__ __launch_bounds__(320) void k_combine_asp(
    const _Float16* __restrict__ hpadA, const int* __restrict__ lens,
    _Float16* __restrict__ aspc, float* __restrict__ a_avg)
{
  int b = blockIdx.x, tid = threadIdx.x;
  if (tid >= NH) return;
  int al = lens[2*NB + b];
  const float alinv = 1.f / (float)al;
  const int c = tid >> 4, ww = tid & 15;
  float sumF = 0.f, sumB = 0.f;
  for (int a = 0; a < NA; a++) {
    float vf = (a < al) ? (float)hpadA[(((size_t)(a*2 + 0)*HCH + c)*256 + b)*16 + ww] : 0.f;
    int tb0 = al - 1 - a; int tb = tb0 < 0 ? 0 : (tb0 > NA-1 ? NA-1 : tb0);
    float vb = (a < al) ? (float)hpadA[(((size_t)(tb*2 + 1)*HCH + c)*256 + b)*16 + ww] : 0.f;
    aspc[((size_t)b*NA + a)*600 + tid]      = (_Float16)vf;
    aspc[((size_t)b*NA + a)*600 + NH + tid] = (_Float16)vb;
    sumF += vf; sumB += vb;
  }
  a_avg[(size_t)b*600 + tid]      = sumF * alinv;
  a_avg[(size_t)b*600 + NH + tid] = sumB * alinv;
}

// ---------------- K6: s1 = a_avg@w1 ; s2 = c_avg@w2 ----------------
__global__ void k_sw(const float* __restrict__ a_avg, const float* __restrict__ c_avg,
                     const float* __restrict__ w1, const float* __restrict__ w2,
                     float* __restrict__ s1, float* __restrict__ s2) {
  __shared__ float src[8][600];
  int bg = blockIdx.x * 8, which = blockIdx.y, tid = threadIdx.x;
  const float* sp = which ? c_avg : a_avg;
  const float* w  = which ? w2 : w1;
  float* outp     = which ? s2 : s1;
  for (int u = tid; u < 8*600; u += 640) {
    int q = u / 600, dd = u - q*600;
    src[q][dd] = sp[(long)(bg + q)*600 + dd];
  }
  __syncthreads();
  int j = tid;
  if (j >= 600) return;
  float acc[8] = {0,0,0,0,0,0,0,0};
  for (int dd = 0; dd < 600; dd++) {
    float wvv = w[dd*600 + j];
    #pragma unroll
    for (int q = 0; q < 8; q++) acc[q] += src[q][dd] * wvv;
  }
  #pragma unroll
  for (int q = 0; q < 8; q++) outp[(long)(bg + q)*600 + j] = acc[q];
}

// ---------------- K7/K8/K9 merged: grid (256 b, 3 role), 128 thr ----------------
// role 0: alpha1+mca (k_att_ctx) ; role 1: alpha2+mcc (128-thr rewrite of
// k_att_asp, same lane-strided summation order) ; role 2: u tensor (k_u).
__global__ __launch_bounds__(128) void k_att3(
    const _Float16* __restrict__ ctxT, const _Float16* __restrict__ ctx,
    const _Float16* __restrict__ aspc,
    const float* __restrict__ s1, const float* __restrict__ s2,
    const float* __restrict__ fc1_w, const float* __restrict__ fc1_b,
    float* __restrict__ mca, float* __restrict__ mcc,
    float* __restrict__ mfa, float* __restrict__ mfc)
{
  const int b = blockIdx.x, role = blockIdx.y, tid = threadIdx.x;
  __shared__ float sv[600];
  __shared__ float red[128];
  __shared__ float sc8[8];
  __shared__ float mx, sm;
  __shared__ __align__(16) float aspl[4800];
  __shared__ float ua8[8];
  __shared__ float qa8[8];
  __shared__ float pal[128][8];

  if (role == 0) {
    // ---- alpha1 + mca ----
    for (int u = tid; u < 600; u += 128) sv[u] = s1[(long)b*600 + u];
    __syncthreads();
    float sc = 0.f;
    for (int dd = 0; dd < 600; dd++) sc += sv[dd] * (float)ctxT[((long)b*600 + dd)*NS + tid];
    red[tid] = sc; __syncthreads();
    if (tid == 0) { float m = -1e30f; for (int i = 0; i < 128; i++) m = fmaxf(m, red[i]); mx = m; }
    __syncthreads();
    float e = __expf(sc - mx);
    red[tid] = e; __syncthreads();
    if (tid == 0) { float s = 0.f; for (int i = 0; i < 128; i++) s += red[i]; sm = s; }
    __syncthreads();
    float alpha = e / sm;
    red[tid] = alpha; __syncthreads();
    for (int i = 0; i < 5; i++) {
      int j = tid + i*128;
      if (j < 600) {
        float acc = 0.f;
        for (int s2i = 0; s2i < NS; s2i++) acc += red[s2i] * (float)ctx[((long)b*NS + s2i)*600 + j];
        mca[(long)b*600 + j] = acc;
      }
    }
  } else if (role == 1) {
    // ---- alpha2 + mcc (2 waves x 4 aspects; same 64-lane dot order) ----
    for (int u = tid; u < 600; u += 128) sv[u] = s2[(long)b*600 + u];
    __syncthreads();
    const int wvv = tid >> 6, lane = tid & 63;
    for (int q = 0; q < 4; q++) {
      int a = wvv*4 + q;
      float p = 0.f;
      for (int dd = lane; dd < 600; dd += 64) p += sv[dd] * (float)aspc[((long)b*NA + a)*600 + dd];
      #pragma unroll
      for (int off = 32; off; off >>= 1) p += __shfl_down(p, off);
      if (lane == 0) sc8[a] = p;
    }
    __syncthreads();
    float m = -1e30f;
    #pragma unroll
    for (int a = 0; a < 8; a++) m = fmaxf(m, sc8[a]);
    float es[8]; float ssum = 0.f;
    #pragma unroll
    for (int a = 0; a < 8; a++) { es[a] = __expf(sc8[a] - m); ssum += es[a]; }
    float inv = 1.f / ssum;
    for (int i = 0; i < 5; i++) {
      int j = tid + i*128;
      if (j < 600) {
        float acc = 0.f;
        #pragma unroll
        for (int a = 0; a < 8; a++) acc += es[a]*inv * (float)aspc[((long)b*NA + a)*600 + j];
        mcc[(long)b*600 + j] = acc;
      }
    }
  } else {
    // ---- u tensor -> mfa, mfc (tid == s) ----
    for (int u = tid; u < 4800; u += 128) {
      int a = u / 600, dd = u - a*600;
      aspl[dd*8 + a] = (float)aspc[((long)b*NA + a)*600 + dd];
    }
    __syncthreads();
    const float* wc = fc1_w;
    const float* wa = fc1_w + 600;
    const float* wm = fc1_w + 1200;
    {
      int wvv = tid >> 6, lane = tid & 63;
      for (int q = 0; q < 4; q++) {
        int a = wvv*4 + q;
        float p = 0.f;
        for (int dd = lane; dd < 600; dd += 64) p += wa[dd] * aspl[dd*8 + a];
        #pragma unroll
        for (int off = 32; off; off >>= 1) p += __shfl_down(p, off);
        if (lane == 0) ua8[a] = p;
      }
    }
    __syncthreads();
    float x8[8] = {0,0,0,0,0,0,0,0};
    float uc = 0.f;
    for (int dd = 0; dd < 600; dd++) {
      float cv = (float)ctxT[((long)b*600 + dd)*NS + tid];
      uc += cv * wc[dd];
      float cm = cv * wm[dd];
      float4 a03 = *(const float4*)&aspl[dd*8];
      float4 a47 = *(const float4*)&aspl[dd*8 + 4];
      x8[0] += cm*a03.x; x8[1] += cm*a03.y; x8[2] += cm*a03.z; x8[3] += cm*a03.w;
      x8[4] += cm*a47.x; x8[5] += cm*a47.y; x8[6] += cm*a47.z; x8[7] += cm*a47.w;
    }
    float fb = fc1_b[0];
    float u8v[8]; float umax = -1e30f;
    #pragma unroll
    for (int a = 0; a < 8; a++) { u8v[a] = uc + ua8[a] + x8[a] + fb; umax = fmaxf(umax, u8v[a]); }
    float pa[8]; float psum = 0.f;
    #pragma unroll
    for (int a = 0; a < 8; a++) { pa[a] = __expf(u8v[a] - umax); psum += pa[a]; }
    float pin = 1.f / psum;
    #pragma unroll
    for (int a = 0; a < 8; a++) pal[tid][a] = pa[a] * pin;
    red[tid] = umax;
    __syncthreads();
    if (tid == 0) { float m = -1e30f; for (int i = 0; i < 128; i++) m = fmaxf(m, red[i]); mx = m; }
    if (tid < 8) { float s = 0.f; for (int i = 0; i < 128; i++) s += pal[i][tid]; qa8[tid] = s * (1.f/128.f); }
    __syncthreads();
    float e = __expf(umax - mx);
    red[tid] = e;
    __syncthreads();
    if (tid == 0) { float s = 0.f; for (int i = 0; i < 128; i++) s += red[i]; sm = s; }
    __syncthreads();
    float alpha = e / sm;
    red[tid] = alpha;
    __syncthreads();
    for (int i = 0; i < 5; i++) {
      int j = tid + i*128;
      if (j < 600) {
        float am = 0.f;
        for (int s2i = 0; s2i < NS; s2i++) am += red[s2i] * (float)ctx[((long)b*NS + s2i)*600 + j];
        float4 a03 = *(const float4*)&aspl[j*8];
        float4 a47 = *(const float4*)&aspl[j*8 + 4];
        mfa[(long)b*600 + j] = am;
        mfc[(long)b*600 + j] = qa8[0]*a03.x + qa8[1]*a03.y + qa8[2]*a03.z + qa8[3]*a03.w
                             + qa8[4]*a47.x + qa8[5]*a47.y + qa8[6]*a47.z + qa8[7]*a47.w;
      }
    }
  }
}

// ---------------- K10: final FC + softmax ----------------
__global__ void k_final(const float* __restrict__ mca, const float* __restrict__ mcc,
                        const float* __restrict__ mfa, const float* __restrict__ mfc,
                        const float* __restrict__ fc2_w, const float* __restrict__ fc2_b,
                        float* __restrict__ out) {
  int b = blockIdx.x, tid = threadIdx.x, c = tid >> 6, lane = tid & 63;
  __shared__ float lg[3];
  float p = 0.f;
  for (int u = lane; u < 2400; u += 64) {
    int piece = u / 600;
    int jj = u - piece*600;
    const float* src = (piece == 0) ? mca : (piece == 1) ? mcc : (piece == 2) ? mfa : mfc;
    p += src[(long)b*600 + jj] * fc2_w[c*2400 + u];
  }
  #pragma unroll
  for (int off = 32; off; off >>= 1) p += __shfl_down(p, off);
  if (lane == 0) lg[c] = p + fc2_b[c];
  __syncthreads();
  if (tid == 0) {
    float m = fmaxf(lg[0], fmaxf(lg[1], lg[2]));
    float e0 = __expf(lg[0]-m), e1 = __expf(lg[1]-m), e2 = __expf(lg[2]-m);
    float s = e0 + e1 + e2;
    out[b*3 + 0] = e0/s; out[b*3 + 1] = e1/s; out[b*3 + 2] = e2/s;
  }
}

// ---------------- host ----------------
extern "C" void kernel_launch(void* const* d_in, const int* in_sizes, int n_in,
                              void* d_out, int out_size, void* d_ws, size_t ws_size,
                              hipStream_t stream)
{
  const int*   text    = (const int*)d_in[0];
  const int*   aspect  = (const int*)d_in[1];
  const int*   left    = (const int*)d_in[2];
  const float* emb     = (const float*)d_in[3];
  const float* Wih_f   = (const float*)d_in[4];
  const float* Whh_f   = (const float*)d_in[5];
  const float* bih_f   = (const float*)d_in[6];
  const float* bhh_f   = (const float*)d_in[7];
  const float* Wih_b   = (const float*)d_in[8];
  const float* Whh_b   = (const float*)d_in[9];
  const float* bih_b   = (const float*)d_in[10];
  const float* bhh_b   = (const float*)d_in[11];
  const float* w1      = (const float*)d_in[12];
  const float* w2      = (const float*)d_in[13];
  const float* fc1_w   = (const float*)d_in[14];
  const float* fc1_b   = (const float*)d_in[15];
  const float* fc2_w   = (const float*)d_in[16];
  const float* fc2_b   = (const float*)d_in[17];
  float* out = (float*)d_out;

  char* base = (char*)d_ws;
  size_t off = 0;
  auto alloc = [&](size_t bytes) -> void* {
    void* p = base + off;
    off = (off + bytes + 255) & ~(size_t)255;
    return p;
  };
  int*      lens     = (int*)     alloc(3 * NB * sizeof(int));
  int*      flags    = (int*)     alloc((size_t)16*128 * sizeof(int));            // 8 KB padded
  float*    bias_sum = (float*)   alloc(NPAD * sizeof(float));
  _Float16* Wih_frag = (_Float16*)alloc((size_t)152*10*512 * sizeof(_Float16));   // 1.56 MB
  _Float16* Whh_frag = (_Float16*)alloc((size_t)152*10*512 * sizeof(_Float16));   // 1.56 MB
  float*    c_avg    = (float*)   alloc((size_t)NB*600 * sizeof(float));
  float*    a_avg    = (float*)   alloc((size_t)NB*600 * sizeof(float));
  float*    s1       = (float*)   alloc((size_t)NB*600 * sizeof(float));
  float*    s2       = (float*)   alloc((size_t)NB*600 * sizeof(float));
  float*    mca      = (float*)   alloc((size_t)NB*600 * sizeof(float));
  float*    mcc      = (float*)   alloc((size_t)NB*600 * sizeof(float));
  float*    mfa      = (float*)   alloc((size_t)NB*600 * sizeof(float));
  float*    mfc      = (float*)   alloc((size_t)NB*600 * sizeof(float));
  _Float16* hpadC    = (_Float16*)alloc((size_t)NS*2*HCH*HSL * sizeof(_Float16)); // 41.9 MB
  _Float16* hpadA    = (_Float16*)alloc((size_t)NA*2*HCH*HSL * sizeof(_Float16)); // 2.62 MB
  // emb16 (20.5 MB) overlays hpadC: used only by cvt_emb+inproj (before scan)
  _Float16* emb16    = hpadC;
  // BIG region: Pc (159.4 MB) + Pa (10 MB); ctx/ctxT/aspc (81 MB) overlay Pc later
  _Float16* Pc = (_Float16*)alloc((size_t)2*NS*NB*PD * sizeof(_Float16));
  _Float16* Pa = (_Float16*)alloc((size_t)2*NA*NB*PD * sizeof(_Float16));
  _Float16* ctx  = Pc;
  _Float16* ctxT = ctx  + (size_t)NB*NS*600;
  _Float16* aspc = ctxT + (size_t)NB*NS*600;
  if (ws_size < off) return;  // clean zero-output signal instead of OOB

  k_lengths<<<1, 256, 0, stream>>>(text, aspect, left, lens);
  k_cvt_emb<<<2048, 256, 0, stream>>>(emb, emb16);
  k_cvt_w<<<dim3(512, 3), 256, 0, stream>>>(Wih_f, Wih_b, Whh_f, Whh_b,
                                            bih_f, bhh_f, bih_b, bhh_b,
                                            Wih_frag, Whh_frag, bias_sum);
  k_inproj<<<dim3(272, 19), 256, 0, stream>>>(emb16, text, aspect, Wih_frag, bias_sum,
                                              lens, Pc, Pa);

  hipMemsetAsync(flags, 0, (size_t)16*128 * sizeof(int), stream);
  k_lstm_scan<<<304, 256, 0, stream>>>(Pc, Pa, Whh_frag, lens, hpadC, hpadA, flags);

  k_ctx_fused<<<256, 256, 0, stream>>>(hpadC, lens, ctx, ctxT, c_avg);
  k_combine_asp<<<256, 320, 0, stream>>>(hpadA, lens, aspc, a_avg);
  k_sw<<<dim3(32, 2), 640, 0, stream>>>(a_avg, c_avg, w1, w2, s1, s2);
  k_att3<<<dim3(256, 3), 128, 0, stream>>>(ctxT, ctx, aspc, s1, s2,
                                           fc1_w, fc1_b, mca, mcc, mfa, mfc);
  k_final<<<256, 192, 0, stream>>>(mca, mcc, mfa, mfc, fc2_w, fc2_b, out);
}

// Round 23
// 992.945 us; speedup vs baseline: 1.2258x; 1.0313x over previous
//
#include <hip/hip_runtime.h>
#include <hip/hip_bf16.h>
#include <hip/hip_fp16.h>

// ---------------------------------------------------------------------------
// MGAN forward. fp16 MFMA; persistent LSTM scan, XCD-colocated sync groups.
//   B=256 S=128 A=8 L=32 D=H=300 NC=3 VOCAB=32000
// MFMA 16x16x32_f16 fragment scheme (validated rounds 2-22).
// P scan-order: Pscan[d][t'][b][1216]. Both weights fragment-major.
// Scan: ONE launch, 304 blocks, XCD swizzle; r19 protocol (best measured:
// scan ~516us): wave-poll consumers (RELAXED/AGENT, quorum 19), block-drain
// producers (__syncthreads + single thread0 relaxed add, padded flag region).
// r23: (a) prologue merged into ONE k_prep dispatch (lengths + emb cvt +
// Wih/Whh frag cvt + bias) — 3074 blocks, role by block range; (b) ctx_fused
// and combine_asp merged into grid(256,2) — independent bodies run
// concurrently. No arithmetic changes anywhere.
// ---------------------------------------------------------------------------

#define NB   256
#define NS   128
#define NA   8
#define NL   32
#define ND   300
#define NH   300
#define NPAD  2432      // 2*4*304 (bias/Wih padded n-space)
#define KP    320
#define TOK_CTX 32768
#define PD    1216      // per-dir gate row: 4*304
#define HCH   20        // h chunks per (t,d): 20*16 = 320 k-range
#define HSL   4096      // 256*16 halves per chunk

typedef _Float16 half8 __attribute__((ext_vector_type(8)));
typedef float    f32x4 __attribute__((ext_vector_type(4)));

__device__ __forceinline__ float fast_tanh(float x) {
  float e = __expf(-2.f * x);          // inf-safe: e=inf -> -1, e=0 -> +1
  return 2.f / (1.f + e) - 1.f;
}

// ---------------- K0: merged prologue ----------------
// blocks [0,2048): emb f32->fp16 (K pad 300->320)
// blocks [2048,2560): Wih_frag ; [2560,3072): Whh_frag
// block 3072: bias_sum ; block 3073: lengths
__global__ __launch_bounds__(256) void k_prep(
    const float* __restrict__ emb, _Float16* __restrict__ emb16,
    const int* __restrict__ text, const int* __restrict__ aspect,
    const int* __restrict__ left, int* __restrict__ lens,
    const float* __restrict__ Wih_f, const float* __restrict__ Wih_b,
    const float* __restrict__ Whh_f, const float* __restrict__ Whh_b,
    const float* __restrict__ bih_f, const float* __restrict__ bhh_f,
    const float* __restrict__ bih_b, const float* __restrict__ bhh_b,
    _Float16* __restrict__ Wih_frag, _Float16* __restrict__ Whh_frag,
    float* __restrict__ bias_sum)
{
  const int blk = blockIdx.x;
  if (blk < 2048) {
    const long N = (long)32000 * KP;
    for (long i = (long)blk*256 + threadIdx.x; i < N; i += (long)2048*256) {
      long v = i / KP; int k = (int)(i - v*KP);
      emb16[i] = (k < ND) ? (_Float16)emb[v*ND + k] : (_Float16)0.f;
    }
  } else if (blk < 3072) {
    const int y  = (blk - 2048) >> 9;     // 0: Wih, 1: Whh
    const int bx = (blk - 2048) & 511;
    const float* sf = y ? Whh_f : Wih_f;
    const float* sb = y ? Whh_b : Wih_b;
    _Float16* dst = y ? Whh_frag : Wih_frag;
    const long N = (long)152*10*512;   // 778240
    for (long i = (long)bx*256 + threadIdx.x; i < N; i += (long)512*256) {
      long q = i >> 9; int r512 = (int)(i & 511);
      int l = r512 >> 3, e = r512 & 7;
      int k0 = (int)(q % 10);
      int ntile = (int)(q / 10);
      int n = ntile*16 + (l & 15);
      int k = k0*32 + (l >> 4)*8 + e;
      int d = n / PD; int rem = n - d*PD;
      int g = rem / 304; int jj = rem - g*304;
      float v = 0.f;
      if (jj < NH && k < NH) {
        const float* src = d ? sb : sf;
        v = src[(long)(g*NH + jj)*NH + k];
      }
      dst[i] = (_Float16)v;
    }
  } else if (blk == 3072) {
    for (int i = threadIdx.x; i < NPAD; i += 256) {
      int d = i / PD; int rem = i - d*PD;
      int g = rem / 304; int jj = rem - g*304;
      float v = 0.f;
      if (jj < NH) {
        v = d ? (bih_b[g*NH + jj] + bhh_b[g*NH + jj]) : (bih_f[g*NH + jj] + bhh_f[g*NH + jj]);
      }
      bias_sum[i] = v;
    }
  } else {
    int b = threadIdx.x;
    if (b < NB) {
      int ll = 0; for (int i = 0; i < NL; i++) ll += (left[b*NL + i] != 0);
      int cl = 0; for (int i = 0; i < NS; i++) cl += (text[b*NS + i] != 0);
      int al = 0; for (int i = 0; i < NA; i++) al += (aspect[b*NA + i] != 0);
      lens[b] = ll; lens[NB + b] = cl; lens[2*NB + b] = al;
    }
  }
}

// ---------------- K1: input projection GEMM (emb16 gather) ----------------
__global__ __launch_bounds__(256) void k_inproj(
    const _Float16* __restrict__ emb16, const int* __restrict__ text, const int* __restrict__ aspect,
    const _Float16* __restrict__ Wih_frag, const float* __restrict__ bias_sum,
    const int* __restrict__ lens,
    _Float16* __restrict__ Pc, _Float16* __restrict__ Pa)
{
  const int l = threadIdx.x & 63, w = threadIdx.x >> 6;
  const int m0 = blockIdx.x * 128, n0 = blockIdx.y * 128;
  const int lrow = l & 15, lk = (l >> 4) * 8;
  __shared__ __align__(16) _Float16 Cs[128*136];

  const _Float16* ap[2];
  #pragma unroll
  for (int q = 0; q < 2; q++) {
    int r = m0 + (2*w + q)*16 + lrow;
    int tok;
    if (r < TOK_CTX) { int t = r >> 8, b = r & 255; tok = text[b*NS + t]; }
    else { int rr = r - TOK_CTX; int t = rr >> 8, b = rr & 255; tok = aspect[b*NA + t]; }
    ap[q] = emb16 + (long)tok*KP + lk;
  }
  const _Float16* bp = Wih_frag + (size_t)(n0 >> 4)*10*512 + l*8;

  f32x4 acc[2][8];
  #pragma unroll
  for (int q = 0; q < 2; q++)
    #pragma unroll
    for (int nt = 0; nt < 8; nt++) acc[q][nt] = (f32x4){0.f,0.f,0.f,0.f};

  #pragma unroll
  for (int k0 = 0; k0 < 10; k0++) {
    half8 a0 = *(const half8*)(ap[0] + k0*32);
    half8 a1 = *(const half8*)(ap[1] + k0*32);
    #pragma unroll
    for (int nt = 0; nt < 8; nt++) {
      half8 bb = *(const half8*)(bp + (size_t)(nt*10 + k0)*512);
      acc[0][nt] = __builtin_amdgcn_mfma_f32_16x16x32_f16(a0, bb, acc[0][nt], 0, 0, 0);
      acc[1][nt] = __builtin_amdgcn_mfma_f32_16x16x32_f16(a1, bb, acc[1][nt], 0, 0, 0);
    }
  }

  #pragma unroll
  for (int nt = 0; nt < 8; nt++) {
    float bias = bias_sum[n0 + nt*16 + lrow];
    #pragma unroll
    for (int q = 0; q < 2; q++) {
      int lr = (2*w + q)*16 + (l>>4)*4;
      #pragma unroll
      for (int r = 0; r < 4; r++)
        Cs[(lr + r)*136 + nt*16 + lrow] = (_Float16)(acc[q][nt][r] + bias);
    }
  }
  __syncthreads();

  const bool isCtx = (m0 < TOK_CTX);
  _Float16* __restrict__ Pdst = isCtx ? Pc : Pa;
  const int T2 = isCtx ? NS : NA;
  const int mrel = isCtx ? m0 : (m0 - TOK_CTX);
  const int tq = mrel >> 8;
  const int b_base = mrel & 255;
  const int lenoff = isCtx ? NB : 2*NB;
  const int chunk = l & 15;
  const int col = n0 + chunk*8;
  const int d = (col >= PD) ? 1 : 0;
  const int rem = col - d*PD;
  #pragma unroll
  for (int it = 0; it < 8; it++) {
    const int row = w*32 + it*4 + (l >> 4);
    const int b = b_base + row;
    int tp = tq; bool doit = true;
    if (d == 1) {
      int len = lens[lenoff + b];
      if (tq < len) tp = len - 1 - tq; else doit = false;
    }
    if (doit) {
      half8 v = *(const half8*)&Cs[row*136 + chunk*8];
      *(half8*)&Pdst[((size_t)(d*T2 + tp)*256 + b)*PD + rem] = v;
    }
  }
}

// ---------------- K2: persistent LSTM scan, wave-poll (AGENT scope) ----------
__global__ __launch_bounds__(256) void k_lstm_scan(
    const _Float16* __restrict__ Pc, const _Float16* __restrict__ Pa,
    const _Float16* __restrict__ Whh_frag, const int* __restrict__ lens,
    _Float16* __restrict__ hpadC, _Float16* __restrict__ hpadA,
    int* __restrict__ flags)   // [16*128] ints, zeroed before launch
{
  const int lin = blockIdx.x;
  const int xcd = lin & 7;
  const int kk2 = lin >> 3;        // 0..37
  const int half = kk2 / 19;
  const int js = kk2 - half*19;
  const int g  = xcd + 8*half;     // 0..15
  const int which = g >> 3;
  const int d  = (g >> 2) & 1;
  const int mg = g & 3;

  const int l = threadIdx.x & 63, w = threadIdx.x >> 6;
  const int T = which ? NA : NS;
  const _Float16* __restrict__ Pbase = which ? Pa : Pc;
  const int* __restrict__ lenp = lens + (which ? 2*NB : NB);
  _Float16* __restrict__ hpad = which ? hpadA : hpadC;
  int* __restrict__ flg = flags + g*128;   // this group's private flag region

  const int lrow = l & 15, lk = (l >> 4)*8, mrow = l >> 4;
  const int b0 = mg*64 + w*16;
  const int cbase = lk >> 4;   // 0/1
  const int koff  = lk & 8;

  // preload this block's Whh fragments into registers (40 x half8)
  half8 wf[10][4];
  #pragma unroll
  for (int k0 = 0; k0 < 10; k0++)
    #pragma unroll
    for (int gg = 0; gg < 4; gg++)
      wf[k0][gg] = *(const half8*)(Whh_frag +
          ((((size_t)(d*4 + gg)*19 + js)*10 + k0) << 9) + l*8);

  float cst[4];
  int   lenv[4];
  #pragma unroll
  for (int r = 0; r < 4; r++) { cst[r] = 0.f; lenv[r] = lenp[b0 + mrow*4 + r]; }

  for (int t = 0; t < T; t++) {
    // prefetch this step's P gates (independent of h; hides the spin)
    const size_t slab = (size_t)(d*T + t)*256;
    float pre[4][4];
    #pragma unroll
    for (int r = 0; r < 4; r++) {
      const int b = b0 + mrow*4 + r;
      const _Float16* Pr = Pbase + (slab + b)*PD + js*16 + lrow;
      pre[r][0] = (float)Pr[0];
      pre[r][1] = (float)Pr[304];
      pre[r][2] = (float)Pr[608];
      pre[r][3] = (float)Pr[912];
    }

    f32x4 accA[4], accB[4];
    #pragma unroll
    for (int gg = 0; gg < 4; gg++) {
      accA[gg] = (f32x4){0.f,0.f,0.f,0.f};
      accB[gg] = (f32x4){0.f,0.f,0.f,0.f};
    }
    float hp[4] = {0.f, 0.f, 0.f, 0.f};

    if (t > 0) {
      // wave-decoupled poll: lane 0 of each wave spins (AGENT scope -> L2,
      // sees other blocks' adds); wave proceeds on exit. h visibility is
      // structural (step-unique single-writer L2 lines).
      if (l == 0) {
        int* fp = &flg[t-1];
        while (__hip_atomic_load(fp, __ATOMIC_RELAXED, __HIP_MEMORY_SCOPE_AGENT) < 19)
          __builtin_amdgcn_s_sleep(1);
      }
      const _Float16* __restrict__ hprev = hpad + (size_t)((t-1)*2 + d)*HCH*HSL;
      #pragma unroll
      for (int r = 0; r < 4; r++)
        hp[r] = (float)hprev[(size_t)js*HSL + (b0 + mrow*4 + r)*16 + lrow];
      const _Float16* hb = hprev + (size_t)(b0 + lrow)*16 + koff;
      #pragma unroll
      for (int k0 = 0; k0 < 10; k0 += 2) {
        half8 aE = *(const half8*)(hb + (size_t)(2*k0 + cbase)*HSL);
        half8 aO = *(const half8*)(hb + (size_t)(2*(k0+1) + cbase)*HSL);
        #pragma unroll
        for (int gg = 0; gg < 4; gg++) {
          accA[gg] = __builtin_amdgcn_mfma_f32_16x16x32_f16(aE, wf[k0][gg],   accA[gg], 0, 0, 0);
          accB[gg] = __builtin_amdgcn_mfma_f32_16x16x32_f16(aO, wf[k0+1][gg], accB[gg], 0, 0, 0);
        }
      }
    }

    // pointwise: 4 cells per thread; write h2 to this step's unique slab
    _Float16* __restrict__ hw = hpad + (size_t)(t*2 + d)*HCH*HSL + (size_t)js*HSL;
    #pragma unroll
    for (int r = 0; r < 4; r++) {
      const int b = b0 + mrow*4 + r;
      float gi = (accA[0][r] + accB[0][r]) + pre[r][0];
      float gf = (accA[1][r] + accB[1][r]) + pre[r][1];
      float gg2 = (accA[2][r] + accB[2][r]) + pre[r][2];
      float go = (accA[3][r] + accB[3][r]) + pre[r][3];
      float si = 1.f/(1.f + __expf(-gi));
      float sf = 1.f/(1.f + __expf(-gf));
      float so = 1.f/(1.f + __expf(-go));
      float cn = sf*cst[r] + si*fast_tanh(gg2);
      float hn = so*fast_tanh(cn);
      bool mt = t < lenv[r];
      float h2 = mt ? hn : hp[r];
      cst[r] = mt ? cn : cst[r];
      hw[(size_t)b*16 + lrow] = (_Float16)h2;
    }

    __syncthreads();   // drains all waves' h stores to L2 before the add
    if (threadIdx.x == 0)
      __hip_atomic_fetch_add(&flg[t], 1,
                             __ATOMIC_RELAXED, __HIP_MEMORY_SCOPE_AGENT);
  }
}

// ---------------- K3: merged ctx_fused (role 0) + combine_asp (role 1) ----------
// grid (256 b, 2 role), 320 thr.
__global__ __launch_bounds__(320) void k_combine2(
    const _Float16* __restrict__ hpadC, const _Float16* __restrict__ hpadA,
    const int* __restrict__ lens,
    _Float16* __restrict__ ctx, _Float16* __restrict__ ctxT, float* __restrict__ c_avg,
    _Float16* __restrict__ aspc, float* __restrict__ a_avg)
{
  const int b = blockIdx.x, role = blockIdx.y, tid = threadIdx.x;
  __shared__ float wgt_s[128];
  __shared__ int   tbv[128];
  __shared__ _Float16 tl[128][62];

  if (role == 0) {
    const int cl = lens[NB + b];
    if (tid < 128) {
      const int ll = lens[b], al = lens[2*NB + b];
      float clf = (float)cl, llf = (float)ll, alf = (float)al, tf = (float)tid;
      float denom = clf - alf + 1.f;
      float wgt = (tf < llf) ? (1.f - (llf - tf)/denom)
                : (tf < llf + alf) ? 0.f
                : (tf < clf) ? (1.f - (tf - llf - alf + 1.f)/denom) : 0.f;
      wgt_s[tid] = wgt;
      int tb0 = cl - 1 - tid; tbv[tid] = tb0 < 0 ? 0 : (tb0 > NS-1 ? NS-1 : tb0);
    }
    __syncthreads();
    const float clinv = 1.f / (float)cl;
    for (int c10 = 0; c10 < 10; c10++) {
      const int j0 = c10*60;
      for (int idx = tid; idx < 128*60; idx += 320) {
        int s = idx / 60, jc = idx - s*60;
        int j = j0 + jc;
        float v;
        if (j < NH) {
          int c = j >> 4, ww = j & 15;
          v = (float)hpadC[(((size_t)(s*2 + 0)*HCH + c)*256 + b)*16 + ww];
        } else {
          int j2 = j - NH; int c = j2 >> 4, ww = j2 & 15;
          v = (float)hpadC[(((size_t)(tbv[s]*2 + 1)*HCH + c)*256 + b)*16 + ww];
        }
        v *= wgt_s[s];
        tl[s][jc] = (_Float16)v;
        ctx[((size_t)b*NS + s)*600 + j] = (_Float16)v;
      }
      __syncthreads();
      for (int idx = tid; idx < 60*128; idx += 320) {
        int jc = idx >> 7, s = idx & 127;
        ctxT[((size_t)b*600 + j0 + jc)*NS + s] = tl[s][jc];
      }
      if (tid < 60) {
        float sum = 0.f;
        for (int s = 0; s < 128; s++) sum += (float)tl[s][tid];
        c_avg[(size_t)b*600 + j0 + tid] = sum * clinv;
      }
      __syncthreads();
    }
  } else {
    if (tid >= NH) return;
    int al = lens[2*NB + b];
    const float alinv = 1.f / (float)al;
    const int c = tid >> 4, ww = tid & 15;
    float sumF = 0.f, sumB = 0.f;
    for (int a = 0; a < NA; a++) {
      float vf = (a < al) ? (float)hpadA[(((size_t)(a*2 + 0)*HCH + c)*256 + b)*16 + ww] : 0.f;
      int tb0 = al - 1 - a; int tb = tb0 < 0 ? 0 : (tb0 > NA-1 ? NA-1 : tb0);
      float vb = (a < al) ? (float)hpadA[(((size_t)(tb*2 + 1)*HCH + c)*256 + b)*16 + ww] : 0.f;
      aspc[((size_t)b*NA + a)*600 + tid]      = (_Float16)vf;
      aspc[((size_t)b*NA + a)*600 + NH + tid] = (_Float16)vb;
      sumF += vf; sumB += vb;
    }
    a_avg[(size_t)b*600 + tid]      = sumF * alinv;
    a_avg[(size_t)b*600 + NH + tid] = sumB * alinv;
  }
}

// ---------------- K6: s1 = a_avg@w1 ; s2 = c_avg@w2 ----------------
__global__ void k_sw(const float* __restrict__ a_avg, const float* __restrict__ c_avg,
                     const float* __restrict__ w1, const float* __restrict__ w2,
                     float* __restrict__ s1, float* __restrict__ s2) {
  __shared__ float src[8][600];
  int bg = blockIdx.x * 8, which = blockIdx.y, tid = threadIdx.x;
  const float* sp = which ? c_avg : a_avg;
  const float* w  = which ? w2 : w1;
  float* outp     = which ? s2 : s1;
  for (int u = tid; u < 8*600; u += 640) {
    int q = u / 600, dd = u - q*600;
    src[q][dd] = sp[(long)(bg + q)*600 + dd];
  }
  __syncthreads();
  int j = tid;
  if (j >= 600) return;
  float acc[8] = {0,0,0,0,0,0,0,0};
  for (int dd = 0; dd < 600; dd++) {
    float wvv = w[dd*600 + j];
    #pragma unroll
    for (int q = 0; q < 8; q++) acc[q] += src[q][dd] * wvv;
  }
  #pragma unroll
  for (int q = 0; q < 8; q++) outp[(long)(bg + q)*600 + j] = acc[q];
}

// ---------------- K7/K8/K9 merged: grid (256 b, 3 role), 128 thr ----------------
__global__ __launch_bounds__(128) void k_att3(
    const _Float16* __restrict__ ctxT, const _Float16* __restrict__ ctx,
    const _Float16* __restrict__ aspc,
    const float* __restrict__ s1, const float* __restrict__ s2,
    const float* __restrict__ fc1_w, const float* __restrict__ fc1_b,
    float* __restrict__ mca, float* __restrict__ mcc,
    float* __restrict__ mfa, float* __restrict__ mfc)
{
  const int b = blockIdx.x, role = blockIdx.y, tid = threadIdx.x;
  __shared__ float sv[600];
  __shared__ float red[128];
  __shared__ float sc8[8];
  __shared__ float mx, sm;
  __shared__ __align__(16) float aspl[4800];
  __shared__ float ua8[8];
  __shared__ float qa8[8];
  __shared__ float pal[128][8];

  if (role == 0) {
    for (int u = tid; u < 600; u += 128) sv[u] = s1[(long)b*600 + u];
    __syncthreads();
    float sc = 0.f;
    for (int dd = 0; dd < 600; dd++) sc += sv[dd] * (float)ctxT[((long)b*600 + dd)*NS + tid];
    red[tid] = sc; __syncthreads();
    if (tid == 0) { float m = -1e30f; for (int i = 0; i < 128; i++) m = fmaxf(m, red[i]); mx = m; }
    __syncthreads();
    float e = __expf(sc - mx);
    red[tid] = e; __syncthreads();
    if (tid == 0) { float s = 0.f; for (int i = 0; i < 128; i++) s += red[i]; sm = s; }
    __syncthreads();
    float alpha = e / sm;
    red[tid] = alpha; __syncthreads();
    for (int i = 0; i < 5; i++) {
      int j = tid + i*128;
      if (j < 600) {
        float acc = 0.f;
        for (int s2i = 0; s2i < NS; s2i++) acc += red[s2i] * (float)ctx[((long)b*NS + s2i)*600 + j];
        mca[(long)b*600 + j] = acc;
      }
    }
  } else if (role == 1) {
    for (int u = tid; u < 600; u += 128) sv[u] = s2[(long)b*600 + u];
    __syncthreads();
    const int wvv = tid >> 6, lane = tid & 63;
    for (int q = 0; q < 4; q++) {
      int a = wvv*4 + q;
      float p = 0.f;
      for (int dd = lane; dd < 600; dd += 64) p += sv[dd] * (float)aspc[((long)b*NA + a)*600 + dd];
      #pragma unroll
      for (int off = 32; off; off >>= 1) p += __shfl_down(p, off);
      if (lane == 0) sc8[a] = p;
    }
    __syncthreads();
    float m = -1e30f;
    #pragma unroll
    for (int a = 0; a < 8; a++) m = fmaxf(m, sc8[a]);
    float es[8]; float ssum = 0.f;
    #pragma unroll
    for (int a = 0; a < 8; a++) { es[a] = __expf(sc8[a] - m); ssum += es[a]; }
    float inv = 1.f / ssum;
    for (int i = 0; i < 5; i++) {
      int j = tid + i*128;
      if (j < 600) {
        float acc = 0.f;
        #pragma unroll
        for (int a = 0; a < 8; a++) acc += es[a]*inv * (float)aspc[((long)b*NA + a)*600 + j];
        mcc[(long)b*600 + j] = acc;
      }
    }
  } else {
    for (int u = tid; u < 4800; u += 128) {
      int a = u / 600, dd = u - a*600;
      aspl[dd*8 + a] = (float)aspc[((long)b*NA + a)*600 + dd];
    }
    __syncthreads();
    const float* wc = fc1_w;
    const float* wa = fc1_w + 600;
    const float* wm = fc1_w + 1200;
    {
      int wvv = tid >> 6, lane = tid & 63;
      for (int q = 0; q < 4; q++) {
        int a = wvv*4 + q;
        float p = 0.f;
        for (int dd = lane; dd < 600; dd += 64) p += wa[dd] * aspl[dd*8 + a];
        #pragma unroll
        for (int off = 32; off; off >>= 1) p += __shfl_down(p, off);
        if (lane == 0) ua8[a] = p;
      }
    }
    __syncthreads();
    float x8[8] = {0,0,0,0,0,0,0,0};
    float uc = 0.f;
    for (int dd = 0; dd < 600; dd++) {
      float cv = (float)ctxT[((long)b*600 + dd)*NS + tid];
      uc += cv * wc[dd];
      float cm = cv * wm[dd];
      float4 a03 = *(const float4*)&aspl[dd*8];
      float4 a47 = *(const float4*)&aspl[dd*8 + 4];
      x8[0] += cm*a03.x; x8[1] += cm*a03.y; x8[2] += cm*a03.z; x8[3] += cm*a03.w;
      x8[4] += cm*a47.x; x8[5] += cm*a47.y; x8[6] += cm*a47.z; x8[7] += cm*a47.w;
    }
    float fb = fc1_b[0];
    float u8v[8]; float umax = -1e30f;
    #pragma unroll
    for (int a = 0; a < 8; a++) { u8v[a] = uc + ua8[a] + x8[a] + fb; umax = fmaxf(umax, u8v[a]); }
    float pa[8]; float psum = 0.f;
    #pragma unroll
    for (int a = 0; a < 8; a++) { pa[a] = __expf(u8v[a] - umax); psum += pa[a]; }
    float pin = 1.f / psum;
    #pragma unroll
    for (int a = 0; a < 8; a++) pal[tid][a] = pa[a] * pin;
    red[tid] = umax;
    __syncthreads();
    if (tid == 0) { float m = -1e30f; for (int i = 0; i < 128; i++) m = fmaxf(m, red[i]); mx = m; }
    if (tid < 8) { float s = 0.f; for (int i = 0; i < 128; i++) s += pal[i][tid]; qa8[tid] = s * (1.f/128.f); }
    __syncthreads();
    float e = __expf(umax - mx);
    red[tid] = e;
    __syncthreads();
    if (tid == 0) { float s = 0.f; for (int i = 0; i < 128; i++) s += red[i]; sm = s; }
    __syncthreads();
    float alpha = e / sm;
    red[tid] = alpha;
    __syncthreads();
    for (int i = 0; i < 5; i++) {
      int j = tid + i*128;
      if (j < 600) {
        float am = 0.f;
        for (int s2i = 0; s2i < NS; s2i++) am += red[s2i] * (float)ctx[((long)b*NS + s2i)*600 + j];
        float4 a03 = *(const float4*)&aspl[j*8];
        float4 a47 = *(const float4*)&aspl[j*8 + 4];
        mfa[(long)b*600 + j] = am;
        mfc[(long)b*600 + j] = qa8[0]*a03.x + qa8[1]*a03.y + qa8[2]*a03.z + qa8[3]*a03.w
                             + qa8[4]*a47.x + qa8[5]*a47.y + qa8[6]*a47.z + qa8[7]*a47.w;
      }
    }
  }
}

// ---------------- K10: final FC + softmax ----------------
__global__ void k_final(const float* __restrict__ mca, const float* __restrict__ mcc,
                        const float* __restrict__ mfa, const float* __restrict__ mfc,
                        const float* __restrict__ fc2_w, const float* __restrict__ fc2_b,
                        float* __restrict__ out) {
  int b = blockIdx.x, tid = threadIdx.x, c = tid >> 6, lane = tid & 63;
  __shared__ float lg[3];
  float p = 0.f;
  for (int u = lane; u < 2400; u += 64) {
    int piece = u / 600;
    int jj = u - piece*600;
    const float* src = (piece == 0) ? mca : (piece == 1) ? mcc : (piece == 2) ? mfa : mfc;
    p += src[(long)b*600 + jj] * fc2_w[c*2400 + u];
  }
  #pragma unroll
  for (int off = 32; off; off >>= 1) p += __shfl_down(p, off);
  if (lane == 0) lg[c] = p + fc2_b[c];
  __syncthreads();
  if (tid == 0) {
    float m = fmaxf(lg[0], fmaxf(lg[1], lg[2]));
    float e0 = __expf(lg[0]-m), e1 = __expf(lg[1]-m), e2 = __expf(lg[2]-m);
    float s = e0 + e1 + e2;
    out[b*3 + 0] = e0/s; out[b*3 + 1] = e1/s; out[b*3 + 2] = e2/s;
  }
}

// ---------------- host ----------------
extern "C" void kernel_launch(void* const* d_in, const int* in_sizes, int n_in,
                              void* d_out, int out_size, void* d_ws, size_t ws_size,
                              hipStream_t stream)
{
  const int*   text    = (const int*)d_in[0];
  const int*   aspect  = (const int*)d_in[1];
  const int*   left    = (const int*)d_in[2];
  const float* emb     = (const float*)d_in[3];
  const float* Wih_f   = (const float*)d_in[4];
  const float* Whh_f   = (const float*)d_in[5];
  const float* bih_f   = (const float*)d_in[6];
  const float* bhh_f   = (const float*)d_in[7];
  const float* Wih_b   = (const float*)d_in[8];
  const float* Whh_b   = (const float*)d_in[9];
  const float* bih_b   = (const float*)d_in[10];
  const float* bhh_b   = (const float*)d_in[11];
  const float* w1      = (const float*)d_in[12];
  const float* w2      = (const float*)d_in[13];
  const float* fc1_w   = (const float*)d_in[14];
  const float* fc1_b   = (const float*)d_in[15];
  const float* fc2_w   = (const float*)d_in[16];
  const float* fc2_b   = (const float*)d_in[17];
  float* out = (float*)d_out;

  char* base = (char*)d_ws;
  size_t off = 0;
  auto alloc = [&](size_t bytes) -> void* {
    void* p = base + off;
    off = (off + bytes + 255) & ~(size_t)255;
    return p;
  };
  int*      lens     = (int*)     alloc(3 * NB * sizeof(int));
  int*      flags    = (int*)     alloc((size_t)16*128 * sizeof(int));            // 8 KB padded
  float*    bias_sum = (float*)   alloc(NPAD * sizeof(float));
  _Float16* Wih_frag = (_Float16*)alloc((size_t)152*10*512 * sizeof(_Float16));   // 1.56 MB
  _Float16* Whh_frag = (_Float16*)alloc((size_t)152*10*512 * sizeof(_Float16));   // 1.56 MB
  float*    c_avg    = (float*)   alloc((size_t)NB*600 * sizeof(float));
  float*    a_avg    = (float*)   alloc((size_t)NB*600 * sizeof(float));
  float*    s1       = (float*)   alloc((size_t)NB*600 * sizeof(float));
  float*    s2       = (float*)   alloc((size_t)NB*600 * sizeof(float));
  float*    mca      = (float*)   alloc((size_t)NB*600 * sizeof(float));
  float*    mcc      = (float*)   alloc((size_t)NB*600 * sizeof(float));
  float*    mfa      = (float*)   alloc((size_t)NB*600 * sizeof(float));
  float*    mfc      = (float*)   alloc((size_t)NB*600 * sizeof(float));
  _Float16* hpadC    = (_Float16*)alloc((size_t)NS*2*HCH*HSL * sizeof(_Float16)); // 41.9 MB
  _Float16* hpadA    = (_Float16*)alloc((size_t)NA*2*HCH*HSL * sizeof(_Float16)); // 2.62 MB
  // emb16 (20.5 MB) overlays hpadC: used only by prep+inproj (before scan)
  _Float16* emb16    = hpadC;
  // BIG region: Pc (159.4 MB) + Pa (10 MB); ctx/ctxT/aspc (81 MB) overlay Pc later
  _Float16* Pc = (_Float16*)alloc((size_t)2*NS*NB*PD * sizeof(_Float16));
  _Float16* Pa = (_Float16*)alloc((size_t)2*NA*NB*PD * sizeof(_Float16));
  _Float16* ctx  = Pc;
  _Float16* ctxT = ctx  + (size_t)NB*NS*600;
  _Float16* aspc = ctxT + (size_t)NB*NS*600;
  if (ws_size < off) return;  // clean zero-output signal instead of OOB

  k_prep<<<3074, 256, 0, stream>>>(emb, emb16, text, aspect, left, lens,
                                   Wih_f, Wih_b, Whh_f, Whh_b,
                                   bih_f, bhh_f, bih_b, bhh_b,
                                   Wih_frag, Whh_frag, bias_sum);
  k_inproj<<<dim3(272, 19), 256, 0, stream>>>(emb16, text, aspect, Wih_frag, bias_sum,
                                              lens, Pc, Pa);

  hipMemsetAsync(flags, 0, (size_t)16*128 * sizeof(int), stream);
  k_lstm_scan<<<304, 256, 0, stream>>>(Pc, Pa, Whh_frag, lens, hpadC, hpadA, flags);

  k_combine2<<<dim3(256, 2), 320, 0, stream>>>(hpadC, hpadA, lens,
                                               ctx, ctxT, c_avg, aspc, a_avg);
  k_sw<<<dim3(32, 2), 640, 0, stream>>>(a_avg, c_avg, w1, w2, s1, s2);
  k_att3<<<dim3(256, 3), 128, 0, stream>>>(ctxT, ctx, aspc, s1, s2,
                                           fc1_w, fc1_b, mca, mcc, mfa, mfc);
  k_final<<<256, 192, 0, stream>>>(mca, mcc, mfa, mfc, fc2_w, fc2_b, out);
}